// Round 5
// baseline (591.614 us; speedup 1.0000x reference)
//
#include <hip/hip_runtime.h>
#include <hip/hip_bf16.h>
#include <math.h>
#include <stdio.h>

// order-preserving float -> uint encoding for atomicMax
__device__ __forceinline__ unsigned encf(float v) {
    unsigned u = __float_as_uint(v);
    return (u & 0x80000000u) ? ~u : (u | 0x80000000u);
}
__device__ __forceinline__ float decf(unsigned k) {
    unsigned u = (k & 0x80000000u) ? (k ^ 0x80000000u) : ~k;
    return __uint_as_float(u);
}

// ---------------- GEMM: C[M,N] = A[M,K] * B[K,N] (+bias, relu) ----------------
// 64x64 tile, BK=16, 256 threads, 4x4 microtile, fp32, float4 staging.
template <bool BIASRELU>
__global__ __launch_bounds__(256) void gemm64(const float* __restrict__ A,
                                              const float* __restrict__ B,
                                              const float* __restrict__ bias,
                                              float* __restrict__ C,
                                              int M, int Nn, int K) {
    __shared__ float As[16][65];
    __shared__ float Bs[16][65];
    const int tid = threadIdx.x;
    const int tx = tid & 15, ty = tid >> 4;
    const int row0 = blockIdx.x * 64;
    const int col0 = blockIdx.y * 64;
    const int idx = tid * 4;
    const int am = idx >> 4, ak = idx & 15;
    const int bk = idx >> 6, bn = idx & 63;

    float acc[4][4] = {};
    for (int k0 = 0; k0 < K; k0 += 16) {
        const int gr = row0 + am;
        float4 a4 = make_float4(0.f, 0.f, 0.f, 0.f);
        if (gr < M) a4 = *(const float4*)(A + (size_t)gr * K + k0 + ak);
        As[ak + 0][am] = a4.x; As[ak + 1][am] = a4.y;
        As[ak + 2][am] = a4.z; As[ak + 3][am] = a4.w;
        const float4 b4 = *(const float4*)(B + (size_t)(k0 + bk) * Nn + col0 + bn);
        Bs[bk][bn + 0] = b4.x; Bs[bk][bn + 1] = b4.y;
        Bs[bk][bn + 2] = b4.z; Bs[bk][bn + 3] = b4.w;
        __syncthreads();
#pragma unroll
        for (int kk = 0; kk < 16; kk++) {
            float av[4], bv[4];
#pragma unroll
            for (int i = 0; i < 4; i++) av[i] = As[kk][ty * 4 + i];
#pragma unroll
            for (int j = 0; j < 4; j++) bv[j] = Bs[kk][tx * 4 + j];
#pragma unroll
            for (int i = 0; i < 4; i++)
#pragma unroll
                for (int j = 0; j < 4; j++) acc[i][j] = fmaf(av[i], bv[j], acc[i][j]);
        }
        __syncthreads();
    }
#pragma unroll
    for (int i = 0; i < 4; i++) {
        const int r = row0 + ty * 4 + i;
        if (r >= M) continue;
#pragma unroll
        for (int j = 0; j < 4; j++) {
            const int c = col0 + tx * 4 + j;
            float v = acc[i][j];
            if (BIASRELU) { v += bias[c]; v = v > 0.f ? v : 0.f; }
            C[(size_t)r * Nn + c] = v;
        }
    }
}

// ---------------- per-node attention dots: as_=h.a_src, ad_=h.a_dst ----------
__global__ __launch_bounds__(256) void dots_kernel(const float* __restrict__ h,
                                                   const float* __restrict__ asrc,
                                                   const float* __restrict__ adst,
                                                   float* __restrict__ as_,
                                                   float* __restrict__ ad_, int N) {
    const int wave = threadIdx.x >> 6, lane = threadIdx.x & 63;
    const int n = blockIdx.x * 4 + wave;
    if (n >= N) return;
    const float* row = h + (size_t)n * 256;
    float s1 = 0.f, s2 = 0.f;
#pragma unroll
    for (int f = 0; f < 256; f += 64) {
        const float x = row[f + lane];
        s1 = fmaf(x, asrc[f + lane], s1);
        s2 = fmaf(x, adst[f + lane], s2);
    }
#pragma unroll
    for (int off = 32; off; off >>= 1) {
        s1 += __shfl_down(s1, off);
        s2 += __shfl_down(s2, off);
    }
    if (lane == 0) { as_[n] = s1; ad_[n] = s2; }
}

// ---------------- init ----------------
__global__ void init3_kernel(int* __restrict__ deg, unsigned* __restrict__ mkey,
                             float* __restrict__ denom, int N) {
    const int i = blockIdx.x * blockDim.x + threadIdx.x;
    if (i < N) { deg[i] = 0; mkey[i] = 0u; denom[i] = 0.f; }
}
__global__ void init2_kernel(unsigned* __restrict__ mkey, float* __restrict__ denom, int N) {
    const int i = blockIdx.x * blockDim.x + threadIdx.x;
    if (i < N) { mkey[i] = 0u; denom[i] = 0.f; }
}

// ---------------- CSR build ----------------
__global__ void count_kernel(const int* __restrict__ dstA, int* __restrict__ deg, int E, int Etot) {
    const int e = blockIdx.x * blockDim.x + threadIdx.x;
    if (e >= Etot) return;
    const int d = (e < E) ? dstA[e] : (e - E);
    atomicAdd(&deg[d], 1);
}

__global__ __launch_bounds__(1024) void scan_kernel(const int* __restrict__ deg,
                                                    int* __restrict__ offs,
                                                    int* __restrict__ cursor, int N) {
    __shared__ int sums[1024];
    const int t = threadIdx.x;
    const int chunk = (N + 1023) / 1024;
    const int start = t * chunk;
    int s = 0;
    for (int i = 0; i < chunk; i++) {
        const int p = start + i;
        if (p < N) s += deg[p];
    }
    sums[t] = s;
    __syncthreads();
    for (int off = 1; off < 1024; off <<= 1) {
        const int add = (t >= off) ? sums[t - off] : 0;
        __syncthreads();
        sums[t] += add;
        __syncthreads();
    }
    int run = (t > 0) ? sums[t - 1] : 0;
    for (int i = 0; i < chunk; i++) {
        const int p = start + i;
        if (p < N) { offs[p] = run; cursor[p] = run; run += deg[p]; }
    }
    if (t == 0) offs[N] = sums[1023];
}

__global__ void scatter_kernel(const int* __restrict__ srcA, const int* __restrict__ dstA,
                               int* __restrict__ cursor, int* __restrict__ esrc,
                               int* __restrict__ slotmap, int E, int Etot) {
    const int e = blockIdx.x * blockDim.x + threadIdx.x;
    if (e >= Etot) return;
    int s, d;
    if (e < E) { s = srcA[e]; d = dstA[e]; } else { s = d = e - E; }
    const int slot = atomicAdd(&cursor[d], 1);
    esrc[slot] = s;
    slotmap[e] = slot;
}

// ---------------- edge softmax passes ----------------
__global__ void edge_max_kernel(const int* __restrict__ srcA, const int* __restrict__ dstA,
                                const float* __restrict__ as_, const float* __restrict__ ad_,
                                unsigned* __restrict__ mkey, int E, int Etot) {
    const int e = blockIdx.x * blockDim.x + threadIdx.x;
    if (e >= Etot) return;
    int s, d;
    if (e < E) { s = srcA[e]; d = dstA[e]; } else { s = d = e - E; }
    float v = as_[s] + ad_[d];
    v = v > 0.f ? v : 0.2f * v;
    atomicMax(&mkey[d], encf(v));
}

__global__ void edge_w_kernel(const int* __restrict__ srcA, const int* __restrict__ dstA,
                              const float* __restrict__ as_, const float* __restrict__ ad_,
                              const unsigned* __restrict__ mkey, const int* __restrict__ slotmap,
                              float* __restrict__ wsort, float* __restrict__ denom, int E, int Etot) {
    const int e = blockIdx.x * blockDim.x + threadIdx.x;
    if (e >= Etot) return;
    int s, d;
    if (e < E) { s = srcA[e]; d = dstA[e]; } else { s = d = e - E; }
    float v = as_[s] + ad_[d];
    v = v > 0.f ? v : 0.2f * v;
    const float m = decf(mkey[d]);
    const float w = __expf(v - m);
    wsort[slotmap[e]] = w;
    atomicAdd(&denom[d], w);
}

// ---------------- aggregation: xout[n] = relu(sum alpha*h[src] + bias) -------
__global__ __launch_bounds__(256) void agg_kernel(const float* __restrict__ h,
                                                  const int* __restrict__ offs,
                                                  const int* __restrict__ esrc,
                                                  const float* __restrict__ wsort,
                                                  const float* __restrict__ denom,
                                                  const float* __restrict__ bias,
                                                  float* __restrict__ xout, int N) {
    const int n = blockIdx.x;
    const int t = threadIdx.x;
    const float inv = 1.0f / (denom[n] + 1e-16f);
    const int b = offs[n], e2 = offs[n + 1];
    float acc = 0.f;
    for (int j = b; j < e2; j++) {
        const int s = esrc[j];
        const float w = wsort[j] * inv;
        acc = fmaf(w, h[(size_t)s * 256 + t], acc);
    }
    acc += bias[t];
    xout[(size_t)n * 256 + t] = acc > 0.f ? acc : 0.f;
}

// ---------------- final head: tanh(x @ Wm2 + bm2), fp32 OUT ------------------
__global__ __launch_bounds__(256) void final_kernel(const float* __restrict__ x,
                                                    const float* __restrict__ W,
                                                    const float* __restrict__ bias,
                                                    float* __restrict__ out, int N, int A) {
    const int wave = threadIdx.x >> 6, lane = threadIdx.x & 63;
    const int n = blockIdx.x * 4 + wave;
    if (n >= N) return;
    const float* row = x + (size_t)n * 256;
    float p[8] = {};
    for (int k = lane; k < 256; k += 64) {
        const float xv = row[k];
#pragma unroll
        for (int a = 0; a < 8; a++) p[a] = fmaf(xv, W[k * A + a], p[a]);
    }
#pragma unroll
    for (int off = 32; off; off >>= 1)
#pragma unroll
        for (int a = 0; a < 8; a++) p[a] += __shfl_down(p[a], off);
    if (lane == 0) {
        for (int a = 0; a < A; a++) out[(size_t)n * A + a] = tanhf(p[a] + bias[a]);
    }
}

// ---------------- guard probe: prints ONLY if out[0] is zero/NaN -------------
__global__ void guard_kernel(const float* __restrict__ out) {
    if (threadIdx.x != 0 || blockIdx.x != 0) return;
    const float o0 = out[0];
    if (fabsf(o0) > 0.f && o0 == o0) return;
    printf("GUARD o0=%e o1=%e\n", (double)o0, (double)out[1]);
}

extern "C" void kernel_launch(void* const* d_in, const int* in_sizes, int n_in,
                              void* d_out, int out_size, void* d_ws, size_t ws_size,
                              hipStream_t stream) {
    const float* obs = (const float*)d_in[0];
    const int* eidx  = (const int*)d_in[1];
    const float* W1  = (const float*)d_in[2];
    const float* a1s = (const float*)d_in[3];
    const float* a1d = (const float*)d_in[4];
    const float* b1  = (const float*)d_in[5];
    const float* W2  = (const float*)d_in[6];
    const float* a2s = (const float*)d_in[7];
    const float* a2d = (const float*)d_in[8];
    const float* b2v = (const float*)d_in[9];
    const float* Wm1 = (const float*)d_in[10];
    const float* bm1 = (const float*)d_in[11];
    const float* Wm2 = (const float*)d_in[12];
    const float* bm2 = (const float*)d_in[13];
    float* out = (float*)d_out;

    const int Hh = in_sizes[3];            // 256
    const int Dd = in_sizes[2] / Hh;       // 256
    const int N  = in_sizes[0] / Dd;       // 20000
    const int E  = in_sizes[1] / 2;        // 320000
    const int Etot = E + N;                // 340000 (self-loops)
    const int Aout = in_sizes[12] / Hh;    // 8

    const int* srcA = eidx;
    const int* dstA = eidx + E;

    size_t off = 0;
    char* ws = (char*)d_ws;
    auto alloc = [&](size_t bytes) -> char* {
        char* p = ws + off;
        off = (off + bytes + 15) & ~(size_t)15;
        return p;
    };
    float* h     = (float*)alloc((size_t)N * Hh * 4);
    float* xbuf  = (float*)alloc((size_t)N * Hh * 4);
    float* as_   = (float*)alloc((size_t)N * 4);
    float* ad_   = (float*)alloc((size_t)N * 4);
    float* denom = (float*)alloc((size_t)N * 4);
    unsigned* mkey = (unsigned*)alloc((size_t)N * 4);
    int* deg     = (int*)alloc((size_t)N * 4);
    int* offs    = (int*)alloc((size_t)(N + 1) * 4);
    int* cursor  = (int*)alloc((size_t)N * 4);
    int* slotmap = (int*)alloc((size_t)Etot * 4);
    int* esrc    = (int*)alloc((size_t)Etot * 4);
    float* wsort = (float*)alloc((size_t)Etot * 4);

    const int eb = 256;
    const int eg = (Etot + eb - 1) / eb;
    const int ng = (N + 255) / 256;
    const dim3 ggrid((N + 63) / 64, Hh / 64);
    const int nb4 = (N + 3) / 4;

    // ---- CSR build (topology shared by both GAT layers) ----
    init3_kernel<<<ng, 256, 0, stream>>>(deg, mkey, denom, N);
    count_kernel<<<eg, eb, 0, stream>>>(dstA, deg, E, Etot);
    scan_kernel<<<1, 1024, 0, stream>>>(deg, offs, cursor, N);
    scatter_kernel<<<eg, eb, 0, stream>>>(srcA, dstA, cursor, esrc, slotmap, E, Etot);

    // ---- GAT layer 1 ----
    gemm64<false><<<ggrid, 256, 0, stream>>>(obs, W1, nullptr, h, N, Hh, Dd);
    dots_kernel<<<nb4, 256, 0, stream>>>(h, a1s, a1d, as_, ad_, N);
    edge_max_kernel<<<eg, eb, 0, stream>>>(srcA, dstA, as_, ad_, mkey, E, Etot);
    edge_w_kernel<<<eg, eb, 0, stream>>>(srcA, dstA, as_, ad_, mkey, slotmap, wsort, denom, E, Etot);
    agg_kernel<<<N, 256, 0, stream>>>(h, offs, esrc, wsort, denom, b1, xbuf, N);

    // ---- GAT layer 2 ----
    init2_kernel<<<ng, 256, 0, stream>>>(mkey, denom, N);
    gemm64<false><<<ggrid, 256, 0, stream>>>(xbuf, W2, nullptr, h, N, Hh, Hh);
    dots_kernel<<<nb4, 256, 0, stream>>>(h, a2s, a2d, as_, ad_, N);
    edge_max_kernel<<<eg, eb, 0, stream>>>(srcA, dstA, as_, ad_, mkey, E, Etot);
    edge_w_kernel<<<eg, eb, 0, stream>>>(srcA, dstA, as_, ad_, mkey, slotmap, wsort, denom, E, Etot);
    agg_kernel<<<N, 256, 0, stream>>>(h, offs, esrc, wsort, denom, b2v, xbuf, N);

    // ---- MLP head ----
    gemm64<true><<<ggrid, 256, 0, stream>>>(xbuf, Wm1, bm1, h, N, Hh, Hh);
    final_kernel<<<nb4, 256, 0, stream>>>(h, Wm2, bm2, out, N, Aout);

    // ---- guard: silent when healthy ----
    guard_kernel<<<1, 64, 0, stream>>>(out);
}

// Round 6
// 547.251 us; speedup vs baseline: 1.0811x; 1.0811x over previous
//
#include <hip/hip_runtime.h>
#include <hip/hip_bf16.h>
#include <math.h>
#include <stdio.h>

typedef __attribute__((ext_vector_type(8))) short short8;   // 8 bf16 (4 VGPRs)
typedef __attribute__((ext_vector_type(4))) float f32x4;

// ---------------- bf16 hi/lo split helpers (bf16x3 precision trick) ----------
__device__ __forceinline__ void split8(f32x4 a0, f32x4 a1, short8& hi, short8& lo) {
#pragma unroll
    for (int i = 0; i < 8; i++) {
        const float f = (i < 4) ? a0[i] : a1[i - 4];
        const unsigned u = __float_as_uint(f);
        hi[i] = (short)(u >> 16);                       // truncate to bf16
        const float hf = __uint_as_float(u & 0xffff0000u);
        lo[i] = (short)(__float_as_uint(f - hf) >> 16); // residual as bf16
    }
}

// W [K][N] fp32 -> Wt hi/lo bf16 planes, n-major [N][K]
__global__ void prep_wT(const float* __restrict__ W, unsigned short* __restrict__ WtHi,
                        unsigned short* __restrict__ WtLo, int K, int Nn) {
    const int idx = blockIdx.x * blockDim.x + threadIdx.x;
    if (idx >= K * Nn) return;
    const int n = idx / K, k = idx - n * K;
    const float f = W[(size_t)k * Nn + n];
    const unsigned u = __float_as_uint(f);
    WtHi[idx] = (unsigned short)(u >> 16);
    const float hf = __uint_as_float(u & 0xffff0000u);
    WtLo[idx] = (unsigned short)(__float_as_uint(f - hf) >> 16);
}

// ---------------- MFMA GEMM: C[M,N] = A[M,K] * B[K,N] (+bias, relu) ----------
// LDS-free: 64x64 tile/block, 4 waves, each wave 16 rows x 64 cols via 4x
// 16x16x32 bf16 MFMA tiles, bf16x3 split for ~fp32 accuracy.
// A: fp32 row-major (split in-register). B: pre-split bf16 planes [N][K].
template <bool BIASRELU>
__global__ __launch_bounds__(256) void gemm_mfma(const float* __restrict__ A,
                                                 const unsigned short* __restrict__ BtHi,
                                                 const unsigned short* __restrict__ BtLo,
                                                 const float* __restrict__ bias,
                                                 float* __restrict__ C,
                                                 int M, int Nn, int K) {
    const int wave = threadIdx.x >> 6, lane = threadIdx.x & 63;
    const int m16 = lane & 15, quad = lane >> 4;
    const int arow = blockIdx.x * 64 + wave * 16 + m16;
    const int rowc = arow < M ? arow : M - 1;
    const int col0 = blockIdx.y * 64;
    const float* Ap = A + (size_t)rowc * K + quad * 8;
    const unsigned short* BpH = BtHi + (size_t)(col0 + m16) * K + quad * 8;
    const unsigned short* BpL = BtLo + (size_t)(col0 + m16) * K + quad * 8;

    f32x4 acc[4] = {};
    for (int k0 = 0; k0 < K; k0 += 32) {
        const f32x4 a0 = *(const f32x4*)(Ap + k0);
        const f32x4 a1 = *(const f32x4*)(Ap + k0 + 4);
        short8 ahi, alo;
        split8(a0, a1, ahi, alo);
#pragma unroll
        for (int c = 0; c < 4; c++) {
            const short8 bhi = *(const short8*)(BpH + (size_t)(c * 16) * K + k0);
            const short8 blo = *(const short8*)(BpL + (size_t)(c * 16) * K + k0);
            acc[c] = __builtin_amdgcn_mfma_f32_16x16x32_bf16(ahi, bhi, acc[c], 0, 0, 0);
            acc[c] = __builtin_amdgcn_mfma_f32_16x16x32_bf16(ahi, blo, acc[c], 0, 0, 0);
            acc[c] = __builtin_amdgcn_mfma_f32_16x16x32_bf16(alo, bhi, acc[c], 0, 0, 0);
        }
    }
    // C/D layout: col = lane&15, row = quad*4 + reg [m89-verified]
    const int orow_base = blockIdx.x * 64 + wave * 16 + quad * 4;
#pragma unroll
    for (int c = 0; c < 4; c++) {
        const int ocol = col0 + c * 16 + m16;
#pragma unroll
        for (int r = 0; r < 4; r++) {
            const int orow = orow_base + r;
            if (orow < M) {
                float v = acc[c][r];
                if (BIASRELU) { v += bias[ocol]; v = fmaxf(v, 0.f); }
                C[(size_t)orow * Nn + ocol] = v;
            }
        }
    }
}

// ---------------- per-node attention dots: as_=h.a_src, ad_=h.a_dst ----------
__global__ __launch_bounds__(256) void dots_kernel(const float* __restrict__ h,
                                                   const float* __restrict__ asrc,
                                                   const float* __restrict__ adst,
                                                   float* __restrict__ as_,
                                                   float* __restrict__ ad_, int N) {
    const int wave = threadIdx.x >> 6, lane = threadIdx.x & 63;
    const int n = blockIdx.x * 4 + wave;
    if (n >= N) return;
    const float* row = h + (size_t)n * 256;
    float s1 = 0.f, s2 = 0.f;
#pragma unroll
    for (int f = 0; f < 256; f += 64) {
        const float x = row[f + lane];
        s1 = fmaf(x, asrc[f + lane], s1);
        s2 = fmaf(x, adst[f + lane], s2);
    }
#pragma unroll
    for (int off = 32; off; off >>= 1) {
        s1 += __shfl_down(s1, off);
        s2 += __shfl_down(s2, off);
    }
    if (lane == 0) { as_[n] = s1; ad_[n] = s2; }
}

// ---------------- init ----------------
__global__ void init2_kernel(int* __restrict__ deg, float* __restrict__ denom, int N) {
    const int i = blockIdx.x * blockDim.x + threadIdx.x;
    if (i < N) { deg[i] = 0; denom[i] = 0.f; }
}
__global__ void init1_kernel(float* __restrict__ denom, int N) {
    const int i = blockIdx.x * blockDim.x + threadIdx.x;
    if (i < N) denom[i] = 0.f;
}

// ---------------- CSR build ----------------
__global__ void count_kernel(const int* __restrict__ dstA, int* __restrict__ deg, int E, int Etot) {
    const int e = blockIdx.x * blockDim.x + threadIdx.x;
    if (e >= Etot) return;
    const int d = (e < E) ? dstA[e] : (e - E);
    atomicAdd(&deg[d], 1);
}

__global__ __launch_bounds__(1024) void scan_kernel(const int* __restrict__ deg,
                                                    int* __restrict__ offs,
                                                    int* __restrict__ cursor, int N) {
    __shared__ int sums[1024];
    const int t = threadIdx.x;
    const int chunk = (N + 1023) / 1024;
    const int start = t * chunk;
    int s = 0;
    for (int i = 0; i < chunk; i++) {
        const int p = start + i;
        if (p < N) s += deg[p];
    }
    sums[t] = s;
    __syncthreads();
    for (int off = 1; off < 1024; off <<= 1) {
        const int add = (t >= off) ? sums[t - off] : 0;
        __syncthreads();
        sums[t] += add;
        __syncthreads();
    }
    int run = (t > 0) ? sums[t - 1] : 0;
    for (int i = 0; i < chunk; i++) {
        const int p = start + i;
        if (p < N) { offs[p] = run; cursor[p] = run; run += deg[p]; }
    }
    if (t == 0) offs[N] = sums[1023];
}

__global__ void scatter_kernel(const int* __restrict__ srcA, const int* __restrict__ dstA,
                               int* __restrict__ cursor, int* __restrict__ esrc,
                               int* __restrict__ slotmap, int E, int Etot) {
    const int e = blockIdx.x * blockDim.x + threadIdx.x;
    if (e >= Etot) return;
    int s, d;
    if (e < E) { s = srcA[e]; d = dstA[e]; } else { s = d = e - E; }
    const int slot = atomicAdd(&cursor[d], 1);
    esrc[slot] = s;
    slotmap[e] = slot;
}

// ---------------- edge softmax (single pass — no max: e <= ~10, exp safe) ----
__global__ void edge_w_kernel(const int* __restrict__ srcA, const int* __restrict__ dstA,
                              const float* __restrict__ as_, const float* __restrict__ ad_,
                              const int* __restrict__ slotmap,
                              float* __restrict__ wsort, float* __restrict__ denom, int E, int Etot) {
    const int e = blockIdx.x * blockDim.x + threadIdx.x;
    if (e >= Etot) return;
    int s, d;
    if (e < E) { s = srcA[e]; d = dstA[e]; } else { s = d = e - E; }
    float v = as_[s] + ad_[d];
    v = v > 0.f ? v : 0.2f * v;
    const float w = __expf(v);
    wsort[slotmap[e]] = w;
    atomicAdd(&denom[d], w);
}

// ---------------- aggregation: xout[n] = relu(sum alpha*h[src] + bias) -------
__global__ __launch_bounds__(256) void agg_kernel(const float* __restrict__ h,
                                                  const int* __restrict__ offs,
                                                  const int* __restrict__ esrc,
                                                  const float* __restrict__ wsort,
                                                  const float* __restrict__ denom,
                                                  const float* __restrict__ bias,
                                                  float* __restrict__ xout, int N) {
    const int n = blockIdx.x;
    const int t = threadIdx.x;
    const float inv = 1.0f / (denom[n] + 1e-16f);
    const int b = offs[n], e2 = offs[n + 1];
    float acc = 0.f;
    for (int j = b; j < e2; j++) {
        const int s = esrc[j];
        const float w = wsort[j] * inv;
        acc = fmaf(w, h[(size_t)s * 256 + t], acc);
    }
    acc += bias[t];
    xout[(size_t)n * 256 + t] = acc > 0.f ? acc : 0.f;
}

// ---------------- final head: tanh(x @ Wm2 + bm2), fp32 out ------------------
__global__ __launch_bounds__(256) void final_kernel(const float* __restrict__ x,
                                                    const float* __restrict__ W,
                                                    const float* __restrict__ bias,
                                                    float* __restrict__ out, int N, int A) {
    const int wave = threadIdx.x >> 6, lane = threadIdx.x & 63;
    const int n = blockIdx.x * 4 + wave;
    if (n >= N) return;
    const float* row = x + (size_t)n * 256;
    float p[8] = {};
    for (int k = lane; k < 256; k += 64) {
        const float xv = row[k];
#pragma unroll
        for (int a = 0; a < 8; a++) p[a] = fmaf(xv, W[k * A + a], p[a]);
    }
#pragma unroll
    for (int off = 32; off; off >>= 1)
#pragma unroll
        for (int a = 0; a < 8; a++) p[a] += __shfl_down(p[a], off);
    if (lane == 0) {
        for (int a = 0; a < A; a++) out[(size_t)n * A + a] = tanhf(p[a] + bias[a]);
    }
}

// ---------------- silent probes ----------------------------------------------
__device__ __forceinline__ float wdot64(const float* a, const float* b, int K, int bstride) {
    const int lane = threadIdx.x & 63;
    float s = 0.f;
    for (int k = lane; k < K; k += 64) s = fmaf(a[k], b[(size_t)k * bstride], s);
#pragma unroll
    for (int off = 32; off; off >>= 1) s += __shfl_down(s, off);
    return __shfl(s, 0);
}
__global__ void probe_gemm(const float* X, const float* W, const float* h, int K, int Nn) {
    const float h00 = wdot64(X, W, K, Nn);
    const float h05 = wdot64(X, W + 5, K, Nn);
    if ((threadIdx.x & 63) != 0) return;
    const bool bad0 = fabsf(h00 - h[0]) > 5e-3f + 1e-2f * fabsf(h00);
    const bool bad5 = fabsf(h05 - h[5]) > 5e-3f + 1e-2f * fabsf(h05);
    if (bad0 || bad5)
        printf("BADMFMA ref=(%e,%e) got=(%e,%e)\n", (double)h00, (double)h05,
               (double)h[0], (double)h[5]);
}
__global__ void guard_kernel(const float* __restrict__ out) {
    if (threadIdx.x != 0 || blockIdx.x != 0) return;
    const float o0 = out[0];
    if (fabsf(o0) > 0.f && o0 == o0) return;
    printf("GUARD o0=%e o1=%e\n", (double)o0, (double)out[1]);
}

extern "C" void kernel_launch(void* const* d_in, const int* in_sizes, int n_in,
                              void* d_out, int out_size, void* d_ws, size_t ws_size,
                              hipStream_t stream) {
    const float* obs = (const float*)d_in[0];
    const int* eidx  = (const int*)d_in[1];
    const float* W1  = (const float*)d_in[2];
    const float* a1s = (const float*)d_in[3];
    const float* a1d = (const float*)d_in[4];
    const float* b1  = (const float*)d_in[5];
    const float* W2  = (const float*)d_in[6];
    const float* a2s = (const float*)d_in[7];
    const float* a2d = (const float*)d_in[8];
    const float* b2v = (const float*)d_in[9];
    const float* Wm1 = (const float*)d_in[10];
    const float* bm1 = (const float*)d_in[11];
    const float* Wm2 = (const float*)d_in[12];
    const float* bm2 = (const float*)d_in[13];
    float* out = (float*)d_out;

    const int Hh = in_sizes[3];            // 256
    const int Dd = in_sizes[2] / Hh;       // 256
    const int N  = in_sizes[0] / Dd;       // 20000
    const int E  = in_sizes[1] / 2;        // 320000
    const int Etot = E + N;                // 340000 (with self-loops)
    const int Aout = in_sizes[12] / Hh;    // 8

    const int* srcA = eidx;
    const int* dstA = eidx + E;

    size_t off = 0;
    char* ws = (char*)d_ws;
    auto alloc = [&](size_t bytes) -> char* {
        char* p = ws + off;
        off = (off + bytes + 15) & ~(size_t)15;
        return p;
    };
    float* h     = (float*)alloc((size_t)N * Hh * 4);
    float* xbuf  = (float*)alloc((size_t)N * Hh * 4);
    float* as_   = (float*)alloc((size_t)N * 4);
    float* ad_   = (float*)alloc((size_t)N * 4);
    float* denom = (float*)alloc((size_t)N * 4);
    int* deg     = (int*)alloc((size_t)N * 4);
    int* offs    = (int*)alloc((size_t)(N + 1) * 4);
    int* cursor  = (int*)alloc((size_t)N * 4);
    int* slotmap = (int*)alloc((size_t)Etot * 4);
    int* esrc    = (int*)alloc((size_t)Etot * 4);
    float* wsort = (float*)alloc((size_t)Etot * 4);
    const size_t wsz = (size_t)Dd * Hh;    // 65536
    unsigned short* W1tH = (unsigned short*)alloc(wsz * 2);
    unsigned short* W1tL = (unsigned short*)alloc(wsz * 2);
    unsigned short* W2tH = (unsigned short*)alloc(wsz * 2);
    unsigned short* W2tL = (unsigned short*)alloc(wsz * 2);
    unsigned short* WmtH = (unsigned short*)alloc(wsz * 2);
    unsigned short* WmtL = (unsigned short*)alloc(wsz * 2);

    const int eb = 256;
    const int eg = (Etot + eb - 1) / eb;
    const int ng = (N + 255) / 256;
    const int wg = ((int)wsz + 255) / 256;
    const dim3 ggrid((N + 63) / 64, Hh / 64);
    const int nb4 = (N + 3) / 4;

    // ---- weight prep (graph-safe: same work every call) ----
    prep_wT<<<wg, 256, 0, stream>>>(W1, W1tH, W1tL, Dd, Hh);
    prep_wT<<<wg, 256, 0, stream>>>(W2, W2tH, W2tL, Hh, Hh);
    prep_wT<<<wg, 256, 0, stream>>>(Wm1, WmtH, WmtL, Hh, Hh);

    // ---- CSR build (topology shared by both GAT layers) ----
    init2_kernel<<<ng, 256, 0, stream>>>(deg, denom, N);
    count_kernel<<<eg, eb, 0, stream>>>(dstA, deg, E, Etot);
    scan_kernel<<<1, 1024, 0, stream>>>(deg, offs, cursor, N);
    scatter_kernel<<<eg, eb, 0, stream>>>(srcA, dstA, cursor, esrc, slotmap, E, Etot);

    // ---- GAT layer 1 ----
    gemm_mfma<false><<<ggrid, 256, 0, stream>>>(obs, W1tH, W1tL, nullptr, h, N, Hh, Dd);
    probe_gemm<<<1, 64, 0, stream>>>(obs, W1, h, Dd, Hh);
    dots_kernel<<<nb4, 256, 0, stream>>>(h, a1s, a1d, as_, ad_, N);
    edge_w_kernel<<<eg, eb, 0, stream>>>(srcA, dstA, as_, ad_, slotmap, wsort, denom, E, Etot);
    agg_kernel<<<N, 256, 0, stream>>>(h, offs, esrc, wsort, denom, b1, xbuf, N);

    // ---- GAT layer 2 ----
    init1_kernel<<<ng, 256, 0, stream>>>(denom, N);
    gemm_mfma<false><<<ggrid, 256, 0, stream>>>(xbuf, W2tH, W2tL, nullptr, h, N, Hh, Hh);
    dots_kernel<<<nb4, 256, 0, stream>>>(h, a2s, a2d, as_, ad_, N);
    edge_w_kernel<<<eg, eb, 0, stream>>>(srcA, dstA, as_, ad_, slotmap, wsort, denom, E, Etot);
    agg_kernel<<<N, 256, 0, stream>>>(h, offs, esrc, wsort, denom, b2v, xbuf, N);

    // ---- MLP head ----
    gemm_mfma<true><<<ggrid, 256, 0, stream>>>(xbuf, WmtH, WmtL, bm1, h, N, Hh, Hh);
    final_kernel<<<nb4, 256, 0, stream>>>(h, Wm2, bm2, out, N, Aout);

    // ---- silent guard ----
    guard_kernel<<<1, 64, 0, stream>>>(out);
}

// Round 7
// 433.808 us; speedup vs baseline: 1.3638x; 1.2615x over previous
//
#include <hip/hip_runtime.h>
#include <hip/hip_bf16.h>
#include <math.h>
#include <stdio.h>

typedef __attribute__((ext_vector_type(8))) short short8;   // 8 bf16 (4 VGPRs)
typedef __attribute__((ext_vector_type(4))) float f32x4;

// ---------------- bf16 hi/lo split helpers (bf16x3 precision trick) ----------
__device__ __forceinline__ void split8(f32x4 a0, f32x4 a1, short8& hi, short8& lo) {
#pragma unroll
    for (int i = 0; i < 8; i++) {
        const float f = (i < 4) ? a0[i] : a1[i - 4];
        const unsigned u = __float_as_uint(f);
        hi[i] = (short)(u >> 16);                       // truncate to bf16
        const float hf = __uint_as_float(u & 0xffff0000u);
        lo[i] = (short)(__float_as_uint(f - hf) >> 16); // residual as bf16
    }
}

// W [K][N] fp32 -> Wt hi/lo bf16 planes, n-major [N][K]
__global__ void prep_wT(const float* __restrict__ W, unsigned short* __restrict__ WtHi,
                        unsigned short* __restrict__ WtLo, int K, int Nn) {
    const int idx = blockIdx.x * blockDim.x + threadIdx.x;
    if (idx >= K * Nn) return;
    const int n = idx / K, k = idx - n * K;
    const float f = W[(size_t)k * Nn + n];
    const unsigned u = __float_as_uint(f);
    WtHi[idx] = (unsigned short)(u >> 16);
    const float hf = __uint_as_float(u & 0xffff0000u);
    WtLo[idx] = (unsigned short)(__float_as_uint(f - hf) >> 16);
}

// ---------------- MFMA GEMM: C[M,N] = A[M,K] * B[K,N] (+bias, relu) ----------
// LDS-free: 64x64 tile/block, 4 waves, each wave 16 rows x 64 cols via 4x
// 16x16x32 bf16 MFMA tiles, bf16x3 split for ~fp32 accuracy.
template <bool BIASRELU>
__global__ __launch_bounds__(256) void gemm_mfma(const float* __restrict__ A,
                                                 const unsigned short* __restrict__ BtHi,
                                                 const unsigned short* __restrict__ BtLo,
                                                 const float* __restrict__ bias,
                                                 float* __restrict__ C,
                                                 int M, int Nn, int K) {
    const int wave = threadIdx.x >> 6, lane = threadIdx.x & 63;
    const int m16 = lane & 15, quad = lane >> 4;
    const int arow = blockIdx.x * 64 + wave * 16 + m16;
    const int rowc = arow < M ? arow : M - 1;
    const int col0 = blockIdx.y * 64;
    const float* Ap = A + (size_t)rowc * K + quad * 8;
    const unsigned short* BpH = BtHi + (size_t)(col0 + m16) * K + quad * 8;
    const unsigned short* BpL = BtLo + (size_t)(col0 + m16) * K + quad * 8;

    f32x4 acc[4] = {};
    for (int k0 = 0; k0 < K; k0 += 32) {
        const f32x4 a0 = *(const f32x4*)(Ap + k0);
        const f32x4 a1 = *(const f32x4*)(Ap + k0 + 4);
        short8 ahi, alo;
        split8(a0, a1, ahi, alo);
#pragma unroll
        for (int c = 0; c < 4; c++) {
            const short8 bhi = *(const short8*)(BpH + (size_t)(c * 16) * K + k0);
            const short8 blo = *(const short8*)(BpL + (size_t)(c * 16) * K + k0);
            acc[c] = __builtin_amdgcn_mfma_f32_16x16x32_bf16(ahi, bhi, acc[c], 0, 0, 0);
            acc[c] = __builtin_amdgcn_mfma_f32_16x16x32_bf16(ahi, blo, acc[c], 0, 0, 0);
            acc[c] = __builtin_amdgcn_mfma_f32_16x16x32_bf16(alo, bhi, acc[c], 0, 0, 0);
        }
    }
    // C/D layout: col = lane&15, row = quad*4 + reg [m89-verified]
    const int orow_base = blockIdx.x * 64 + wave * 16 + quad * 4;
#pragma unroll
    for (int c = 0; c < 4; c++) {
        const int ocol = col0 + c * 16 + m16;
#pragma unroll
        for (int r = 0; r < 4; r++) {
            const int orow = orow_base + r;
            if (orow < M) {
                float v = acc[c][r];
                if (BIASRELU) { v += bias[ocol]; v = fmaxf(v, 0.f); }
                C[(size_t)orow * Nn + ocol] = v;
            }
        }
    }
}

// ---------------- per-node attention dots: as_=h.a_src, ad_=h.a_dst ----------
__global__ __launch_bounds__(256) void dots_kernel(const float* __restrict__ h,
                                                   const float* __restrict__ asrc,
                                                   const float* __restrict__ adst,
                                                   float* __restrict__ as_,
                                                   float* __restrict__ ad_, int N) {
    const int wave = threadIdx.x >> 6, lane = threadIdx.x & 63;
    const int n = blockIdx.x * 4 + wave;
    if (n >= N) return;
    const float* row = h + (size_t)n * 256;
    float s1 = 0.f, s2 = 0.f;
#pragma unroll
    for (int f = 0; f < 256; f += 64) {
        const float x = row[f + lane];
        s1 = fmaf(x, asrc[f + lane], s1);
        s2 = fmaf(x, adst[f + lane], s2);
    }
#pragma unroll
    for (int off = 32; off; off >>= 1) {
        s1 += __shfl_down(s1, off);
        s2 += __shfl_down(s2, off);
    }
    if (lane == 0) { as_[n] = s1; ad_[n] = s2; }
}

// ---------------- CSR build ----------------
__global__ void init_deg(int* __restrict__ deg, int N) {
    const int i = blockIdx.x * blockDim.x + threadIdx.x;
    if (i < N) deg[i] = 0;
}

__global__ void count_kernel(const int* __restrict__ dstA, int* __restrict__ deg, int E, int Etot) {
    const int e = blockIdx.x * blockDim.x + threadIdx.x;
    if (e >= Etot) return;
    const int d = (e < E) ? dstA[e] : (e - E);
    atomicAdd(&deg[d], 1);
}

__global__ __launch_bounds__(1024) void scan_kernel(const int* __restrict__ deg,
                                                    int* __restrict__ offs,
                                                    int* __restrict__ cursor, int N) {
    __shared__ int sums[1024];
    const int t = threadIdx.x;
    const int chunk = (N + 1023) / 1024;
    const int start = t * chunk;
    int s = 0;
    for (int i = 0; i < chunk; i++) {
        const int p = start + i;
        if (p < N) s += deg[p];
    }
    sums[t] = s;
    __syncthreads();
    for (int off = 1; off < 1024; off <<= 1) {
        const int add = (t >= off) ? sums[t - off] : 0;
        __syncthreads();
        sums[t] += add;
        __syncthreads();
    }
    int run = (t > 0) ? sums[t - 1] : 0;
    for (int i = 0; i < chunk; i++) {
        const int p = start + i;
        if (p < N) { offs[p] = run; cursor[p] = run; run += deg[p]; }
    }
    if (t == 0) offs[N] = sums[1023];
}

__global__ void scatter_kernel(const int* __restrict__ srcA, const int* __restrict__ dstA,
                               int* __restrict__ cursor, int* __restrict__ esrc, int E, int Etot) {
    const int e = blockIdx.x * blockDim.x + threadIdx.x;
    if (e >= Etot) return;
    int s, d;
    if (e < E) { s = srcA[e]; d = dstA[e]; } else { s = d = e - E; }
    const int slot = atomicAdd(&cursor[d], 1);
    esrc[slot] = s;
}

// ---- fused softmax+aggregation: xout[n] = relu(Σ w_j h[s_j] / Σ w_j + bias) -
// w_j = exp(leaky(as[s_j] + ad[n])); no max-subtraction (|e| <= ~10, fp32-safe)
__global__ __launch_bounds__(256) void agg_kernel(const float* __restrict__ h,
                                                  const int* __restrict__ offs,
                                                  const int* __restrict__ esrc,
                                                  const float* __restrict__ as_,
                                                  const float* __restrict__ ad_,
                                                  const float* __restrict__ bias,
                                                  float* __restrict__ xout, int N) {
    const int n = blockIdx.x;
    const int t = threadIdx.x;
    const int b = offs[n], e2 = offs[n + 1];
    const float adn = ad_[n];
    float acc = 0.f, wsum = 0.f;
    int j = b;
    for (; j + 8 <= e2; j += 8) {
        int s[8];
#pragma unroll
        for (int u = 0; u < 8; u++) s[u] = esrc[j + u];
        float hv[8];
#pragma unroll
        for (int u = 0; u < 8; u++) hv[u] = h[(size_t)s[u] * 256 + t];
        float w[8];
#pragma unroll
        for (int u = 0; u < 8; u++) {
            float v = as_[s[u]] + adn;
            v = v > 0.f ? v : 0.2f * v;
            w[u] = __expf(v);
        }
#pragma unroll
        for (int u = 0; u < 8; u++) { acc = fmaf(w[u], hv[u], acc); wsum += w[u]; }
    }
    for (; j < e2; j++) {
        const int s = esrc[j];
        float v = as_[s] + adn;
        v = v > 0.f ? v : 0.2f * v;
        const float w = __expf(v);
        acc = fmaf(w, h[(size_t)s * 256 + t], acc);
        wsum += w;
    }
    const float r = acc / (wsum + 1e-16f) + bias[t];
    xout[(size_t)n * 256 + t] = r > 0.f ? r : 0.f;
}

// ---------------- final head: tanh(x @ Wm2 + bm2), fp32 out ------------------
__global__ __launch_bounds__(256) void final_kernel(const float* __restrict__ x,
                                                    const float* __restrict__ W,
                                                    const float* __restrict__ bias,
                                                    float* __restrict__ out, int N, int A) {
    const int wave = threadIdx.x >> 6, lane = threadIdx.x & 63;
    const int n = blockIdx.x * 4 + wave;
    if (n >= N) return;
    const float* row = x + (size_t)n * 256;
    float p[8] = {};
    for (int k = lane; k < 256; k += 64) {
        const float xv = row[k];
#pragma unroll
        for (int a = 0; a < 8; a++) p[a] = fmaf(xv, W[k * A + a], p[a]);
    }
#pragma unroll
    for (int off = 32; off; off >>= 1)
#pragma unroll
        for (int a = 0; a < 8; a++) p[a] += __shfl_down(p[a], off);
    if (lane == 0) {
        for (int a = 0; a < A; a++) out[(size_t)n * A + a] = tanhf(p[a] + bias[a]);
    }
}

// ---------------- silent guard ----------------------------------------------
__global__ void guard_kernel(const float* __restrict__ out) {
    if (threadIdx.x != 0 || blockIdx.x != 0) return;
    const float o0 = out[0];
    if (fabsf(o0) > 0.f && o0 == o0) return;
    printf("GUARD o0=%e o1=%e\n", (double)o0, (double)out[1]);
}

extern "C" void kernel_launch(void* const* d_in, const int* in_sizes, int n_in,
                              void* d_out, int out_size, void* d_ws, size_t ws_size,
                              hipStream_t stream) {
    const float* obs = (const float*)d_in[0];
    const int* eidx  = (const int*)d_in[1];
    const float* W1  = (const float*)d_in[2];
    const float* a1s = (const float*)d_in[3];
    const float* a1d = (const float*)d_in[4];
    const float* b1  = (const float*)d_in[5];
    const float* W2  = (const float*)d_in[6];
    const float* a2s = (const float*)d_in[7];
    const float* a2d = (const float*)d_in[8];
    const float* b2v = (const float*)d_in[9];
    const float* Wm1 = (const float*)d_in[10];
    const float* bm1 = (const float*)d_in[11];
    const float* Wm2 = (const float*)d_in[12];
    const float* bm2 = (const float*)d_in[13];
    float* out = (float*)d_out;

    const int Hh = in_sizes[3];            // 256
    const int Dd = in_sizes[2] / Hh;       // 256
    const int N  = in_sizes[0] / Dd;       // 20000
    const int E  = in_sizes[1] / 2;        // 320000
    const int Etot = E + N;                // 340000 (with self-loops)
    const int Aout = in_sizes[12] / Hh;    // 8

    const int* srcA = eidx;
    const int* dstA = eidx + E;

    size_t off = 0;
    char* ws = (char*)d_ws;
    auto alloc = [&](size_t bytes) -> char* {
        char* p = ws + off;
        off = (off + bytes + 15) & ~(size_t)15;
        return p;
    };
    float* h     = (float*)alloc((size_t)N * Hh * 4);
    float* xbuf  = (float*)alloc((size_t)N * Hh * 4);
    float* as_   = (float*)alloc((size_t)N * 4);
    float* ad_   = (float*)alloc((size_t)N * 4);
    int* deg     = (int*)alloc((size_t)N * 4);
    int* offs    = (int*)alloc((size_t)(N + 1) * 4);
    int* cursor  = (int*)alloc((size_t)N * 4);
    int* esrc    = (int*)alloc((size_t)Etot * 4);
    const size_t wsz = (size_t)Dd * Hh;    // 65536
    unsigned short* W1tH = (unsigned short*)alloc(wsz * 2);
    unsigned short* W1tL = (unsigned short*)alloc(wsz * 2);
    unsigned short* W2tH = (unsigned short*)alloc(wsz * 2);
    unsigned short* W2tL = (unsigned short*)alloc(wsz * 2);
    unsigned short* WmtH = (unsigned short*)alloc(wsz * 2);
    unsigned short* WmtL = (unsigned short*)alloc(wsz * 2);

    const int eb = 256;
    const int eg = (Etot + eb - 1) / eb;
    const int ng = (N + 255) / 256;
    const int wg = ((int)wsz + 255) / 256;
    const dim3 ggrid((N + 63) / 64, Hh / 64);
    const int nb4 = (N + 3) / 4;

    // ---- weight prep ----
    prep_wT<<<wg, 256, 0, stream>>>(W1, W1tH, W1tL, Dd, Hh);
    prep_wT<<<wg, 256, 0, stream>>>(W2, W2tH, W2tL, Hh, Hh);
    prep_wT<<<wg, 256, 0, stream>>>(Wm1, WmtH, WmtL, Hh, Hh);

    // ---- CSR build (topology shared by both GAT layers) ----
    init_deg<<<ng, 256, 0, stream>>>(deg, N);
    count_kernel<<<eg, eb, 0, stream>>>(dstA, deg, E, Etot);
    scan_kernel<<<1, 1024, 0, stream>>>(deg, offs, cursor, N);
    scatter_kernel<<<eg, eb, 0, stream>>>(srcA, dstA, cursor, esrc, E, Etot);

    // ---- GAT layer 1 ----
    gemm_mfma<false><<<ggrid, 256, 0, stream>>>(obs, W1tH, W1tL, nullptr, h, N, Hh, Dd);
    dots_kernel<<<nb4, 256, 0, stream>>>(h, a1s, a1d, as_, ad_, N);
    agg_kernel<<<N, 256, 0, stream>>>(h, offs, esrc, as_, ad_, b1, xbuf, N);

    // ---- GAT layer 2 ----
    gemm_mfma<false><<<ggrid, 256, 0, stream>>>(xbuf, W2tH, W2tL, nullptr, h, N, Hh, Hh);
    dots_kernel<<<nb4, 256, 0, stream>>>(h, a2s, a2d, as_, ad_, N);
    agg_kernel<<<N, 256, 0, stream>>>(h, offs, esrc, as_, ad_, b2v, xbuf, N);

    // ---- MLP head ----
    gemm_mfma<true><<<ggrid, 256, 0, stream>>>(xbuf, WmtH, WmtL, bm1, h, N, Hh, Hh);
    final_kernel<<<nb4, 256, 0, stream>>>(h, Wm2, bm2, out, N, Aout);

    // ---- silent guard ----
    guard_kernel<<<1, 64, 0, stream>>>(out);
}

// Round 8
// 353.218 us; speedup vs baseline: 1.6749x; 1.2282x over previous
//
#include <hip/hip_runtime.h>
#include <hip/hip_bf16.h>
#include <math.h>
#include <stdio.h>

typedef __attribute__((ext_vector_type(8))) short short8;   // 8 bf16 (4 VGPRs)
typedef __attribute__((ext_vector_type(4))) float f32x4;
typedef __attribute__((ext_vector_type(4))) unsigned short us4;

// W [K][N] fp32 -> Wt hi/lo bf16 planes, n-major [N][K]
__global__ void prep_wT(const float* __restrict__ W, unsigned short* __restrict__ WtHi,
                        unsigned short* __restrict__ WtLo, int K, int Nn) {
    const int idx = blockIdx.x * blockDim.x + threadIdx.x;
    if (idx >= K * Nn) return;
    const int n = idx / K, k = idx - n * K;
    const float f = W[(size_t)k * Nn + n];
    const unsigned u = __float_as_uint(f);
    WtHi[idx] = (unsigned short)(u >> 16);
    const float hf = __uint_as_float(u & 0xffff0000u);
    WtLo[idx] = (unsigned short)(__float_as_uint(f - hf) >> 16);
}

// ---------------- MFMA GEMM: C[M,N] = A[M,K] * B[K,N] (+bias, relu) ----------
// 64x128 tile/block, BK=32, 256 thr (4 waves 2x2: 32 rows x 64 cols each).
// LDS-staged (coalesced global, ds_read_b128 fragments), bf16x3 accuracy.
// LDS rows padded to 40 shorts (80 B): 16B-aligned, worst 2-way bank alias.
#define LP 40
template <bool BIASRELU>
__global__ __launch_bounds__(256) void gemm_mfma(const float* __restrict__ A,
                                                 const unsigned short* __restrict__ BtHi,
                                                 const unsigned short* __restrict__ BtLo,
                                                 const float* __restrict__ bias,
                                                 float* __restrict__ C,
                                                 int M, int Nn, int K) {
    __shared__ unsigned short sAhi[64 * LP], sAlo[64 * LP];
    __shared__ unsigned short sBhi[128 * LP], sBlo[128 * LP];
    const int tid = threadIdx.x;
    const int wave = tid >> 6, lane = tid & 63;
    const int m16 = lane & 15, quad = lane >> 4;
    const int row0 = blockIdx.x * 64, col0 = blockIdx.y * 128;
    // staging map: A -> thread covers rows {tid>>3}+{0,32}, k-span (tid&7)*4
    const int arow = tid >> 3;
    const int akv = (tid & 7) * 4;
    // B -> thread covers tile col tid>>1, k-span (tid&1)*16 .. +16
    const int bn = tid >> 1;
    const int bk = (tid & 1) * 16;
    // wave tile origin: 2x2 wave grid
    const int wr = (wave >> 1) * 32, wc = (wave & 1) * 64;

    f32x4 acc[2][4] = {};
    for (int k0 = 0; k0 < K; k0 += 32) {
        // ---- stage A: fp32 -> hi/lo bf16 ----
#pragma unroll
        for (int i = 0; i < 2; i++) {
            const int r = arow + 32 * i;
            const int grow = row0 + r;
            const int gr = grow < M ? grow : M - 1;
            const float4 a4 = *(const float4*)(A + (size_t)gr * K + k0 + akv);
            const float f[4] = {a4.x, a4.y, a4.z, a4.w};
            us4 hi, lo;
#pragma unroll
            for (int e = 0; e < 4; e++) {
                const unsigned u = __float_as_uint(f[e]);
                hi[e] = (unsigned short)(u >> 16);
                const float hf = __uint_as_float(u & 0xffff0000u);
                lo[e] = (unsigned short)(__float_as_uint(f[e] - hf) >> 16);
            }
            *(us4*)&sAhi[r * LP + akv] = hi;
            *(us4*)&sAlo[r * LP + akv] = lo;
        }
        // ---- stage B: pre-split planes, b128 in/out ----
        {
            const size_t gb = (size_t)(col0 + bn) * K + k0 + bk;
            *(short8*)&sBhi[bn * LP + bk]     = *(const short8*)(BtHi + gb);
            *(short8*)&sBhi[bn * LP + bk + 8] = *(const short8*)(BtHi + gb + 8);
            *(short8*)&sBlo[bn * LP + bk]     = *(const short8*)(BtLo + gb);
            *(short8*)&sBlo[bn * LP + bk + 8] = *(const short8*)(BtLo + gb + 8);
        }
        __syncthreads();
        // ---- fragments + MFMA ----
        short8 bh[4], bl[4];
#pragma unroll
        for (int ni = 0; ni < 4; ni++) {
            const int nb = (wc + ni * 16 + m16) * LP + quad * 8;
            bh[ni] = *(const short8*)&sBhi[nb];
            bl[ni] = *(const short8*)&sBlo[nb];
        }
#pragma unroll
        for (int mi = 0; mi < 2; mi++) {
            const int ab = (wr + mi * 16 + m16) * LP + quad * 8;
            const short8 ah = *(const short8*)&sAhi[ab];
            const short8 al = *(const short8*)&sAlo[ab];
#pragma unroll
            for (int ni = 0; ni < 4; ni++) {
                acc[mi][ni] = __builtin_amdgcn_mfma_f32_16x16x32_bf16(ah, bh[ni], acc[mi][ni], 0, 0, 0);
                acc[mi][ni] = __builtin_amdgcn_mfma_f32_16x16x32_bf16(ah, bl[ni], acc[mi][ni], 0, 0, 0);
                acc[mi][ni] = __builtin_amdgcn_mfma_f32_16x16x32_bf16(al, bh[ni], acc[mi][ni], 0, 0, 0);
            }
        }
        __syncthreads();
    }
    // epilogue: C/D layout col=lane&15, row=quad*4+r [m89-verified]
#pragma unroll
    for (int mi = 0; mi < 2; mi++) {
        const int orow_base = row0 + wr + mi * 16 + quad * 4;
#pragma unroll
        for (int ni = 0; ni < 4; ni++) {
            const int ocol = col0 + wc + ni * 16 + m16;
#pragma unroll
            for (int r = 0; r < 4; r++) {
                const int orow = orow_base + r;
                if (orow < M) {
                    float v = acc[mi][ni][r];
                    if (BIASRELU) { v += bias[ocol]; v = fmaxf(v, 0.f); }
                    C[(size_t)orow * Nn + ocol] = v;
                }
            }
        }
    }
}
#undef LP

// ---------------- per-node attention dots: as_=h.a_src, ad_=h.a_dst ----------
__global__ __launch_bounds__(256) void dots_kernel(const float* __restrict__ h,
                                                   const float* __restrict__ asrc,
                                                   const float* __restrict__ adst,
                                                   float* __restrict__ as_,
                                                   float* __restrict__ ad_, int N) {
    const int wave = threadIdx.x >> 6, lane = threadIdx.x & 63;
    const int n = blockIdx.x * 4 + wave;
    if (n >= N) return;
    const float* row = h + (size_t)n * 256;
    float s1 = 0.f, s2 = 0.f;
#pragma unroll
    for (int f = 0; f < 256; f += 64) {
        const float x = row[f + lane];
        s1 = fmaf(x, asrc[f + lane], s1);
        s2 = fmaf(x, adst[f + lane], s2);
    }
#pragma unroll
    for (int off = 32; off; off >>= 1) {
        s1 += __shfl_down(s1, off);
        s2 += __shfl_down(s2, off);
    }
    if (lane == 0) { as_[n] = s1; ad_[n] = s2; }
}

// ---------------- CSR build ----------------
__global__ void init_deg(int* __restrict__ deg, int N) {
    const int i = blockIdx.x * blockDim.x + threadIdx.x;
    if (i < N) deg[i] = 0;
}

__global__ void count_kernel(const int* __restrict__ dstA, int* __restrict__ deg, int E, int Etot) {
    const int e = blockIdx.x * blockDim.x + threadIdx.x;
    if (e >= Etot) return;
    const int d = (e < E) ? dstA[e] : (e - E);
    atomicAdd(&deg[d], 1);
}

__global__ __launch_bounds__(1024) void scan_kernel(const int* __restrict__ deg,
                                                    int* __restrict__ offs,
                                                    int* __restrict__ cursor, int N) {
    __shared__ int sums[1024];
    const int t = threadIdx.x;
    const int chunk = (N + 1023) / 1024;
    const int start = t * chunk;
    int s = 0;
    for (int i = 0; i < chunk; i++) {
        const int p = start + i;
        if (p < N) s += deg[p];
    }
    sums[t] = s;
    __syncthreads();
    for (int off = 1; off < 1024; off <<= 1) {
        const int add = (t >= off) ? sums[t - off] : 0;
        __syncthreads();
        sums[t] += add;
        __syncthreads();
    }
    int run = (t > 0) ? sums[t - 1] : 0;
    for (int i = 0; i < chunk; i++) {
        const int p = start + i;
        if (p < N) { offs[p] = run; cursor[p] = run; run += deg[p]; }
    }
    if (t == 0) offs[N] = sums[1023];
}

__global__ void scatter_kernel(const int* __restrict__ srcA, const int* __restrict__ dstA,
                               int* __restrict__ cursor, int* __restrict__ esrc, int E, int Etot) {
    const int e = blockIdx.x * blockDim.x + threadIdx.x;
    if (e >= Etot) return;
    int s, d;
    if (e < E) { s = srcA[e]; d = dstA[e]; } else { s = d = e - E; }
    const int slot = atomicAdd(&cursor[d], 1);
    esrc[slot] = s;
}

// ---- fused softmax+aggregation: xout[n] = relu(Σ w_j h[s_j] / Σ w_j + bias) -
__global__ __launch_bounds__(256) void agg_kernel(const float* __restrict__ h,
                                                  const int* __restrict__ offs,
                                                  const int* __restrict__ esrc,
                                                  const float* __restrict__ as_,
                                                  const float* __restrict__ ad_,
                                                  const float* __restrict__ bias,
                                                  float* __restrict__ xout, int N) {
    const int n = blockIdx.x;
    const int t = threadIdx.x;
    const int b = offs[n], e2 = offs[n + 1];
    const float adn = ad_[n];
    float acc = 0.f, wsum = 0.f;
    int j = b;
    for (; j + 8 <= e2; j += 8) {
        int s[8];
#pragma unroll
        for (int u = 0; u < 8; u++) s[u] = esrc[j + u];
        float hv[8];
#pragma unroll
        for (int u = 0; u < 8; u++) hv[u] = h[(size_t)s[u] * 256 + t];
        float w[8];
#pragma unroll
        for (int u = 0; u < 8; u++) {
            float v = as_[s[u]] + adn;
            v = v > 0.f ? v : 0.2f * v;
            w[u] = __expf(v);
        }
#pragma unroll
        for (int u = 0; u < 8; u++) { acc = fmaf(w[u], hv[u], acc); wsum += w[u]; }
    }
    for (; j < e2; j++) {
        const int s = esrc[j];
        float v = as_[s] + adn;
        v = v > 0.f ? v : 0.2f * v;
        const float w = __expf(v);
        acc = fmaf(w, h[(size_t)s * 256 + t], acc);
        wsum += w;
    }
    const float r = acc / (wsum + 1e-16f) + bias[t];
    xout[(size_t)n * 256 + t] = r > 0.f ? r : 0.f;
}

// ---------------- final head: tanh(x @ Wm2 + bm2), fp32 out ------------------
__global__ __launch_bounds__(256) void final_kernel(const float* __restrict__ x,
                                                    const float* __restrict__ W,
                                                    const float* __restrict__ bias,
                                                    float* __restrict__ out, int N, int A) {
    const int wave = threadIdx.x >> 6, lane = threadIdx.x & 63;
    const int n = blockIdx.x * 4 + wave;
    if (n >= N) return;
    const float* row = x + (size_t)n * 256;
    float p[8] = {};
    for (int k = lane; k < 256; k += 64) {
        const float xv = row[k];
#pragma unroll
        for (int a = 0; a < 8; a++) p[a] = fmaf(xv, W[k * A + a], p[a]);
    }
#pragma unroll
    for (int off = 32; off; off >>= 1)
#pragma unroll
        for (int a = 0; a < 8; a++) p[a] += __shfl_down(p[a], off);
    if (lane == 0) {
        for (int a = 0; a < A; a++) out[(size_t)n * A + a] = tanhf(p[a] + bias[a]);
    }
}

// ---------------- silent probes ----------------------------------------------
__device__ __forceinline__ float wdot64(const float* a, const float* b, int K, int bstride) {
    const int lane = threadIdx.x & 63;
    float s = 0.f;
    for (int k = lane; k < K; k += 64) s = fmaf(a[k], b[(size_t)k * bstride], s);
#pragma unroll
    for (int off = 32; off; off >>= 1) s += __shfl_down(s, off);
    return __shfl(s, 0);
}
__global__ void probe_gemm(const float* X, const float* W, const float* h, int K, int Nn) {
    const float h00 = wdot64(X, W, K, Nn);
    const float h05 = wdot64(X, W + 5, K, Nn);
    if ((threadIdx.x & 63) != 0) return;
    const bool bad0 = fabsf(h00 - h[0]) > 5e-3f + 1e-2f * fabsf(h00);
    const bool bad5 = fabsf(h05 - h[5]) > 5e-3f + 1e-2f * fabsf(h05);
    if (bad0 || bad5)
        printf("BADMFMA ref=(%e,%e) got=(%e,%e)\n", (double)h00, (double)h05,
               (double)h[0], (double)h[5]);
}
__global__ void guard_kernel(const float* __restrict__ out) {
    if (threadIdx.x != 0 || blockIdx.x != 0) return;
    const float o0 = out[0];
    if (fabsf(o0) > 0.f && o0 == o0) return;
    printf("GUARD o0=%e o1=%e\n", (double)o0, (double)out[1]);
}

extern "C" void kernel_launch(void* const* d_in, const int* in_sizes, int n_in,
                              void* d_out, int out_size, void* d_ws, size_t ws_size,
                              hipStream_t stream) {
    const float* obs = (const float*)d_in[0];
    const int* eidx  = (const int*)d_in[1];
    const float* W1  = (const float*)d_in[2];
    const float* a1s = (const float*)d_in[3];
    const float* a1d = (const float*)d_in[4];
    const float* b1  = (const float*)d_in[5];
    const float* W2  = (const float*)d_in[6];
    const float* a2s = (const float*)d_in[7];
    const float* a2d = (const float*)d_in[8];
    const float* b2v = (const float*)d_in[9];
    const float* Wm1 = (const float*)d_in[10];
    const float* bm1 = (const float*)d_in[11];
    const float* Wm2 = (const float*)d_in[12];
    const float* bm2 = (const float*)d_in[13];
    float* out = (float*)d_out;

    const int Hh = in_sizes[3];            // 256
    const int Dd = in_sizes[2] / Hh;       // 256
    const int N  = in_sizes[0] / Dd;       // 20000
    const int E  = in_sizes[1] / 2;        // 320000
    const int Etot = E + N;                // 340000 (with self-loops)
    const int Aout = in_sizes[12] / Hh;    // 8

    const int* srcA = eidx;
    const int* dstA = eidx + E;

    size_t off = 0;
    char* ws = (char*)d_ws;
    auto alloc = [&](size_t bytes) -> char* {
        char* p = ws + off;
        off = (off + bytes + 15) & ~(size_t)15;
        return p;
    };
    float* h     = (float*)alloc((size_t)N * Hh * 4);
    float* xbuf  = (float*)alloc((size_t)N * Hh * 4);
    float* as_   = (float*)alloc((size_t)N * 4);
    float* ad_   = (float*)alloc((size_t)N * 4);
    int* deg     = (int*)alloc((size_t)N * 4);
    int* offs    = (int*)alloc((size_t)(N + 1) * 4);
    int* cursor  = (int*)alloc((size_t)N * 4);
    int* esrc    = (int*)alloc((size_t)Etot * 4);
    const size_t wsz = (size_t)Dd * Hh;    // 65536
    unsigned short* W1tH = (unsigned short*)alloc(wsz * 2);
    unsigned short* W1tL = (unsigned short*)alloc(wsz * 2);
    unsigned short* W2tH = (unsigned short*)alloc(wsz * 2);
    unsigned short* W2tL = (unsigned short*)alloc(wsz * 2);
    unsigned short* WmtH = (unsigned short*)alloc(wsz * 2);
    unsigned short* WmtL = (unsigned short*)alloc(wsz * 2);

    const int eb = 256;
    const int eg = (Etot + eb - 1) / eb;
    const int ng = (N + 255) / 256;
    const int wg = ((int)wsz + 255) / 256;
    const dim3 ggrid((N + 63) / 64, Hh / 128);   // 313 x 2 = 626 blocks
    const int nb4 = (N + 3) / 4;

    // ---- weight prep ----
    prep_wT<<<wg, 256, 0, stream>>>(W1, W1tH, W1tL, Dd, Hh);
    prep_wT<<<wg, 256, 0, stream>>>(W2, W2tH, W2tL, Hh, Hh);
    prep_wT<<<wg, 256, 0, stream>>>(Wm1, WmtH, WmtL, Hh, Hh);

    // ---- CSR build (topology shared by both GAT layers) ----
    init_deg<<<ng, 256, 0, stream>>>(deg, N);
    count_kernel<<<eg, eb, 0, stream>>>(dstA, deg, E, Etot);
    scan_kernel<<<1, 1024, 0, stream>>>(deg, offs, cursor, N);
    scatter_kernel<<<eg, eb, 0, stream>>>(srcA, dstA, cursor, esrc, E, Etot);

    // ---- GAT layer 1 ----
    gemm_mfma<false><<<ggrid, 256, 0, stream>>>(obs, W1tH, W1tL, nullptr, h, N, Hh, Dd);
    probe_gemm<<<1, 64, 0, stream>>>(obs, W1, h, Dd, Hh);
    dots_kernel<<<nb4, 256, 0, stream>>>(h, a1s, a1d, as_, ad_, N);
    agg_kernel<<<N, 256, 0, stream>>>(h, offs, esrc, as_, ad_, b1, xbuf, N);

    // ---- GAT layer 2 ----
    gemm_mfma<false><<<ggrid, 256, 0, stream>>>(xbuf, W2tH, W2tL, nullptr, h, N, Hh, Hh);
    dots_kernel<<<nb4, 256, 0, stream>>>(h, a2s, a2d, as_, ad_, N);
    agg_kernel<<<N, 256, 0, stream>>>(h, offs, esrc, as_, ad_, b2v, xbuf, N);

    // ---- MLP head ----
    gemm_mfma<true><<<ggrid, 256, 0, stream>>>(xbuf, WmtH, WmtL, bm1, h, N, Hh, Hh);
    final_kernel<<<nb4, 256, 0, stream>>>(h, Wm2, bm2, out, N, Aout);

    // ---- silent guard ----
    guard_kernel<<<1, 64, 0, stream>>>(out);
}

// Round 9
// 310.713 us; speedup vs baseline: 1.9041x; 1.1368x over previous
//
#include <hip/hip_runtime.h>
#include <hip/hip_bf16.h>
#include <math.h>
#include <stdio.h>

typedef __attribute__((ext_vector_type(8))) short short8;   // 8 bf16 (4 VGPRs)
typedef __attribute__((ext_vector_type(4))) float f32x4;
typedef __attribute__((ext_vector_type(4))) unsigned short us4;
typedef unsigned short ushort_t;

__device__ __forceinline__ float us2f(unsigned short u) {
    return __uint_as_float(((unsigned)u) << 16);
}
__device__ __forceinline__ unsigned short f2us_rtn(float f) {
    return (unsigned short)__bfloat16_as_ushort(__float2bfloat16(f));  // RTN
}

// W [K][N] fp32 -> Wt hi/lo bf16 planes, n-major [N][K]; 3 matrices fused
__global__ void prep3_wT(const float* __restrict__ Wa, const float* __restrict__ Wb,
                         const float* __restrict__ Wc,
                         unsigned short* __restrict__ HiA, unsigned short* __restrict__ LoA,
                         unsigned short* __restrict__ HiB, unsigned short* __restrict__ LoB,
                         unsigned short* __restrict__ HiC, unsigned short* __restrict__ LoC,
                         int K, int Nn) {
    const int tot = K * Nn;
    int idx = blockIdx.x * blockDim.x + threadIdx.x;
    if (idx >= 3 * tot) return;
    const float* W;
    unsigned short *Hi, *Lo;
    if (idx < tot) { W = Wa; Hi = HiA; Lo = LoA; }
    else if (idx < 2 * tot) { W = Wb; Hi = HiB; Lo = LoB; idx -= tot; }
    else { W = Wc; Hi = HiC; Lo = LoC; idx -= 2 * tot; }
    const int n = idx / K, k = idx - n * K;
    const float f = W[(size_t)k * Nn + n];
    const unsigned u = __float_as_uint(f);
    Hi[idx] = (unsigned short)(u >> 16);
    const float hf = __uint_as_float(u & 0xffff0000u);
    Lo[idx] = (unsigned short)(__float_as_uint(f - hf) >> 16);
}

// ---------------- MFMA GEMM: C[M,N] = A[M,K] * B[K,N] (+bias, relu) ----------
// 64x128 tile/block, BK=32, 256 thr (4 waves 2x2). LDS-staged, bf16x3.
// Output stored as bf16 (RTN) — downstream gather/read bytes halve.
#define LP 40
template <bool BIASRELU>
__global__ __launch_bounds__(256) void gemm_mfma(const float* __restrict__ A,
                                                 const unsigned short* __restrict__ BtHi,
                                                 const unsigned short* __restrict__ BtLo,
                                                 const float* __restrict__ bias,
                                                 unsigned short* __restrict__ C,
                                                 int M, int Nn, int K) {
    __shared__ unsigned short sAhi[64 * LP], sAlo[64 * LP];
    __shared__ unsigned short sBhi[128 * LP], sBlo[128 * LP];
    const int tid = threadIdx.x;
    const int wave = tid >> 6, lane = tid & 63;
    const int m16 = lane & 15, quad = lane >> 4;
    const int row0 = blockIdx.x * 64, col0 = blockIdx.y * 128;
    const int arow = tid >> 3;
    const int akv = (tid & 7) * 4;
    const int bn = tid >> 1;
    const int bk = (tid & 1) * 16;
    const int wr = (wave >> 1) * 32, wc = (wave & 1) * 64;

    f32x4 acc[2][4] = {};
    for (int k0 = 0; k0 < K; k0 += 32) {
#pragma unroll
        for (int i = 0; i < 2; i++) {
            const int r = arow + 32 * i;
            const int grow = row0 + r;
            const int gr = grow < M ? grow : M - 1;
            const float4 a4 = *(const float4*)(A + (size_t)gr * K + k0 + akv);
            const float f[4] = {a4.x, a4.y, a4.z, a4.w};
            us4 hi, lo;
#pragma unroll
            for (int e = 0; e < 4; e++) {
                const unsigned u = __float_as_uint(f[e]);
                hi[e] = (unsigned short)(u >> 16);
                const float hf = __uint_as_float(u & 0xffff0000u);
                lo[e] = (unsigned short)(__float_as_uint(f[e] - hf) >> 16);
            }
            *(us4*)&sAhi[r * LP + akv] = hi;
            *(us4*)&sAlo[r * LP + akv] = lo;
        }
        {
            const size_t gb = (size_t)(col0 + bn) * K + k0 + bk;
            *(short8*)&sBhi[bn * LP + bk]     = *(const short8*)(BtHi + gb);
            *(short8*)&sBhi[bn * LP + bk + 8] = *(const short8*)(BtHi + gb + 8);
            *(short8*)&sBlo[bn * LP + bk]     = *(const short8*)(BtLo + gb);
            *(short8*)&sBlo[bn * LP + bk + 8] = *(const short8*)(BtLo + gb + 8);
        }
        __syncthreads();
        short8 bh[4], bl[4];
#pragma unroll
        for (int ni = 0; ni < 4; ni++) {
            const int nb = (wc + ni * 16 + m16) * LP + quad * 8;
            bh[ni] = *(const short8*)&sBhi[nb];
            bl[ni] = *(const short8*)&sBlo[nb];
        }
#pragma unroll
        for (int mi = 0; mi < 2; mi++) {
            const int ab = (wr + mi * 16 + m16) * LP + quad * 8;
            const short8 ah = *(const short8*)&sAhi[ab];
            const short8 al = *(const short8*)&sAlo[ab];
#pragma unroll
            for (int ni = 0; ni < 4; ni++) {
                acc[mi][ni] = __builtin_amdgcn_mfma_f32_16x16x32_bf16(ah, bh[ni], acc[mi][ni], 0, 0, 0);
                acc[mi][ni] = __builtin_amdgcn_mfma_f32_16x16x32_bf16(ah, bl[ni], acc[mi][ni], 0, 0, 0);
                acc[mi][ni] = __builtin_amdgcn_mfma_f32_16x16x32_bf16(al, bh[ni], acc[mi][ni], 0, 0, 0);
            }
        }
        __syncthreads();
    }
    // epilogue: C/D layout col=lane&15, row=quad*4+r [m89-verified]
#pragma unroll
    for (int mi = 0; mi < 2; mi++) {
        const int orow_base = row0 + wr + mi * 16 + quad * 4;
#pragma unroll
        for (int ni = 0; ni < 4; ni++) {
            const int ocol = col0 + wc + ni * 16 + m16;
#pragma unroll
            for (int r = 0; r < 4; r++) {
                const int orow = orow_base + r;
                if (orow < M) {
                    float v = acc[mi][ni][r];
                    if (BIASRELU) { v += bias[ocol]; v = fmaxf(v, 0.f); }
                    C[(size_t)orow * Nn + ocol] = f2us_rtn(v);
                }
            }
        }
    }
}
#undef LP

// ---------------- per-node attention dots (bf16 h) ---------------------------
__global__ __launch_bounds__(256) void dots_kernel(const unsigned short* __restrict__ hb,
                                                   const float* __restrict__ asrc,
                                                   const float* __restrict__ adst,
                                                   float* __restrict__ as_,
                                                   float* __restrict__ ad_, int N) {
    const int wave = threadIdx.x >> 6, lane = threadIdx.x & 63;
    const int n = blockIdx.x * 4 + wave;
    if (n >= N) return;
    const int f = lane * 4;
    const us4 v = *(const us4*)(hb + (size_t)n * 256 + f);
    float s1 = 0.f, s2 = 0.f;
#pragma unroll
    for (int e = 0; e < 4; e++) {
        const float x = us2f(v[e]);
        s1 = fmaf(x, asrc[f + e], s1);
        s2 = fmaf(x, adst[f + e], s2);
    }
#pragma unroll
    for (int off = 32; off; off >>= 1) {
        s1 += __shfl_down(s1, off);
        s2 += __shfl_down(s2, off);
    }
    if (lane == 0) { as_[n] = s1; ad_[n] = s2; }
}

// ---------------- CSR build ----------------
__global__ void init_deg(int* __restrict__ deg, int N) {
    const int i = blockIdx.x * blockDim.x + threadIdx.x;
    if (i < N) deg[i] = 0;
}

__global__ void count_kernel(const int* __restrict__ dstA, int* __restrict__ deg, int E, int Etot) {
    const int e = blockIdx.x * blockDim.x + threadIdx.x;
    if (e >= Etot) return;
    const int d = (e < E) ? dstA[e] : (e - E);
    atomicAdd(&deg[d], 1);
}

__global__ __launch_bounds__(1024) void scan_kernel(const int* __restrict__ deg,
                                                    int* __restrict__ offs,
                                                    int* __restrict__ cursor, int N) {
    __shared__ int sums[1024];
    const int t = threadIdx.x;
    const int chunk = (N + 1023) / 1024;
    const int start = t * chunk;
    int s = 0;
    for (int i = 0; i < chunk; i++) {
        const int p = start + i;
        if (p < N) s += deg[p];
    }
    sums[t] = s;
    __syncthreads();
    for (int off = 1; off < 1024; off <<= 1) {
        const int add = (t >= off) ? sums[t - off] : 0;
        __syncthreads();
        sums[t] += add;
        __syncthreads();
    }
    int run = (t > 0) ? sums[t - 1] : 0;
    for (int i = 0; i < chunk; i++) {
        const int p = start + i;
        if (p < N) { offs[p] = run; cursor[p] = run; run += deg[p]; }
    }
    if (t == 0) offs[N] = sums[1023];
}

__global__ void scatter_kernel(const int* __restrict__ srcA, const int* __restrict__ dstA,
                               int* __restrict__ cursor, int* __restrict__ esrc, int E, int Etot) {
    const int e = blockIdx.x * blockDim.x + threadIdx.x;
    if (e >= Etot) return;
    int s, d;
    if (e < E) { s = srcA[e]; d = dstA[e]; } else { s = d = e - E; }
    const int slot = atomicAdd(&cursor[d], 1);
    esrc[slot] = s;
}

// ---- fused softmax+aggregation over bf16 h: 128 thr/node, 2 feat/thread -----
__global__ __launch_bounds__(128) void agg_kernel(const unsigned short* __restrict__ hb,
                                                  const int* __restrict__ offs,
                                                  const int* __restrict__ esrc,
                                                  const float* __restrict__ as_,
                                                  const float* __restrict__ ad_,
                                                  const float* __restrict__ bias,
                                                  float* __restrict__ xout, int N) {
    const int n = blockIdx.x;
    const int f0 = threadIdx.x * 2;
    const int b = offs[n], e2 = offs[n + 1];
    const float adn = ad_[n];
    float ax = 0.f, ay = 0.f, wsum = 0.f;
    int j = b;
    for (; j + 8 <= e2; j += 8) {
        int s[8];
#pragma unroll
        for (int u = 0; u < 8; u++) s[u] = esrc[j + u];
        unsigned pv[8];
#pragma unroll
        for (int u = 0; u < 8; u++) pv[u] = *(const unsigned*)(hb + (size_t)s[u] * 256 + f0);
        float w[8];
#pragma unroll
        for (int u = 0; u < 8; u++) {
            float v = as_[s[u]] + adn;
            v = v > 0.f ? v : 0.2f * v;
            w[u] = __expf(v);
        }
#pragma unroll
        for (int u = 0; u < 8; u++) {
            ax = fmaf(w[u], us2f((unsigned short)(pv[u] & 0xffffu)), ax);
            ay = fmaf(w[u], us2f((unsigned short)(pv[u] >> 16)), ay);
            wsum += w[u];
        }
    }
    for (; j < e2; j++) {
        const int s = esrc[j];
        float v = as_[s] + adn;
        v = v > 0.f ? v : 0.2f * v;
        const float w = __expf(v);
        const unsigned pv = *(const unsigned*)(hb + (size_t)s * 256 + f0);
        ax = fmaf(w, us2f((unsigned short)(pv & 0xffffu)), ax);
        ay = fmaf(w, us2f((unsigned short)(pv >> 16)), ay);
        wsum += w;
    }
    const float inv = 1.0f / (wsum + 1e-16f);
    const float rx = ax * inv + bias[f0];
    const float ry = ay * inv + bias[f0 + 1];
    xout[(size_t)n * 256 + f0]     = rx > 0.f ? rx : 0.f;
    xout[(size_t)n * 256 + f0 + 1] = ry > 0.f ? ry : 0.f;
}

// ---------------- final head: tanh(x @ Wm2 + bm2), bf16 x, fp32 out ----------
__global__ __launch_bounds__(256) void final_kernel(const unsigned short* __restrict__ xb,
                                                    const float* __restrict__ W,
                                                    const float* __restrict__ bias,
                                                    float* __restrict__ out, int N, int A) {
    const int wave = threadIdx.x >> 6, lane = threadIdx.x & 63;
    const int n = blockIdx.x * 4 + wave;
    if (n >= N) return;
    const int k0 = lane * 4;
    const us4 v = *(const us4*)(xb + (size_t)n * 256 + k0);
    float p[8] = {};
#pragma unroll
    for (int e = 0; e < 4; e++) {
        const float xv = us2f(v[e]);
#pragma unroll
        for (int a = 0; a < 8; a++) p[a] = fmaf(xv, W[(k0 + e) * A + a], p[a]);
    }
#pragma unroll
    for (int off = 32; off; off >>= 1)
#pragma unroll
        for (int a = 0; a < 8; a++) p[a] += __shfl_down(p[a], off);
    if (lane == 0) {
        for (int a = 0; a < A; a++) out[(size_t)n * A + a] = tanhf(p[a] + bias[a]);
    }
}

// ---------------- silent probes ----------------------------------------------
__device__ __forceinline__ float wdot64(const float* a, const float* b, int K, int bstride) {
    const int lane = threadIdx.x & 63;
    float s = 0.f;
    for (int k = lane; k < K; k += 64) s = fmaf(a[k], b[(size_t)k * bstride], s);
#pragma unroll
    for (int off = 32; off; off >>= 1) s += __shfl_down(s, off);
    return __shfl(s, 0);
}
__global__ void probe_gemm(const float* X, const float* W, const unsigned short* hb,
                           int K, int Nn) {
    const float h00 = wdot64(X, W, K, Nn);
    const float h05 = wdot64(X, W + 5, K, Nn);
    if ((threadIdx.x & 63) != 0) return;
    const float g0 = us2f(hb[0]), g5 = us2f(hb[5]);
    const bool bad0 = fabsf(h00 - g0) > 1.5e-2f + 1e-2f * fabsf(h00);
    const bool bad5 = fabsf(h05 - g5) > 1.5e-2f + 1e-2f * fabsf(h05);
    if (bad0 || bad5)
        printf("BADMFMA ref=(%e,%e) got=(%e,%e)\n", (double)h00, (double)h05,
               (double)g0, (double)g5);
}
__global__ void guard_kernel(const float* __restrict__ out) {
    if (threadIdx.x != 0 || blockIdx.x != 0) return;
    const float o0 = out[0];
    if (fabsf(o0) > 0.f && o0 == o0) return;
    printf("GUARD o0=%e o1=%e\n", (double)o0, (double)out[1]);
}

extern "C" void kernel_launch(void* const* d_in, const int* in_sizes, int n_in,
                              void* d_out, int out_size, void* d_ws, size_t ws_size,
                              hipStream_t stream) {
    const float* obs = (const float*)d_in[0];
    const int* eidx  = (const int*)d_in[1];
    const float* W1  = (const float*)d_in[2];
    const float* a1s = (const float*)d_in[3];
    const float* a1d = (const float*)d_in[4];
    const float* b1  = (const float*)d_in[5];
    const float* W2  = (const float*)d_in[6];
    const float* a2s = (const float*)d_in[7];
    const float* a2d = (const float*)d_in[8];
    const float* b2v = (const float*)d_in[9];
    const float* Wm1 = (const float*)d_in[10];
    const float* bm1 = (const float*)d_in[11];
    const float* Wm2 = (const float*)d_in[12];
    const float* bm2 = (const float*)d_in[13];
    float* out = (float*)d_out;

    const int Hh = in_sizes[3];            // 256
    const int Dd = in_sizes[2] / Hh;       // 256
    const int N  = in_sizes[0] / Dd;       // 20000
    const int E  = in_sizes[1] / 2;        // 320000
    const int Etot = E + N;                // 340000 (with self-loops)
    const int Aout = in_sizes[12] / Hh;    // 8

    const int* srcA = eidx;
    const int* dstA = eidx + E;

    size_t off = 0;
    char* ws = (char*)d_ws;
    auto alloc = [&](size_t bytes) -> char* {
        char* p = ws + off;
        off = (off + bytes + 15) & ~(size_t)15;
        return p;
    };
    unsigned short* h = (unsigned short*)alloc((size_t)N * Hh * 2);  // bf16 activations
    float* xbuf  = (float*)alloc((size_t)N * Hh * 4);                // agg out (GEMM A input)
    float* as_   = (float*)alloc((size_t)N * 4);
    float* ad_   = (float*)alloc((size_t)N * 4);
    int* deg     = (int*)alloc((size_t)N * 4);
    int* offs    = (int*)alloc((size_t)(N + 1) * 4);
    int* cursor  = (int*)alloc((size_t)N * 4);
    int* esrc    = (int*)alloc((size_t)Etot * 4);
    const size_t wsz = (size_t)Dd * Hh;    // 65536
    unsigned short* W1tH = (unsigned short*)alloc(wsz * 2);
    unsigned short* W1tL = (unsigned short*)alloc(wsz * 2);
    unsigned short* W2tH = (unsigned short*)alloc(wsz * 2);
    unsigned short* W2tL = (unsigned short*)alloc(wsz * 2);
    unsigned short* WmtH = (unsigned short*)alloc(wsz * 2);
    unsigned short* WmtL = (unsigned short*)alloc(wsz * 2);

    const int eb = 256;
    const int eg = (Etot + eb - 1) / eb;
    const int ng = (N + 255) / 256;
    const dim3 ggrid((N + 63) / 64, Hh / 128);   // 313 x 2
    const int nb4 = (N + 3) / 4;

    // ---- weight prep (all three 256x256 mats in one launch) ----
    const int p3 = (3 * (int)wsz + 255) / 256;
    prep3_wT<<<p3, 256, 0, stream>>>(W1, W2, Wm1, W1tH, W1tL, W2tH, W2tL, WmtH, WmtL, Dd, Hh);

    // ---- CSR build (topology shared by both GAT layers) ----
    init_deg<<<ng, 256, 0, stream>>>(deg, N);
    count_kernel<<<eg, eb, 0, stream>>>(dstA, deg, E, Etot);
    scan_kernel<<<1, 1024, 0, stream>>>(deg, offs, cursor, N);
    scatter_kernel<<<eg, eb, 0, stream>>>(srcA, dstA, cursor, esrc, E, Etot);

    // ---- GAT layer 1 ----
    gemm_mfma<false><<<ggrid, 256, 0, stream>>>(obs, W1tH, W1tL, nullptr, h, N, Hh, Dd);
    probe_gemm<<<1, 64, 0, stream>>>(obs, W1, h, Dd, Hh);
    dots_kernel<<<nb4, 256, 0, stream>>>(h, a1s, a1d, as_, ad_, N);
    agg_kernel<<<N, 128, 0, stream>>>(h, offs, esrc, as_, ad_, b1, xbuf, N);

    // ---- GAT layer 2 ----
    gemm_mfma<false><<<ggrid, 256, 0, stream>>>(xbuf, W2tH, W2tL, nullptr, h, N, Hh, Hh);
    dots_kernel<<<nb4, 256, 0, stream>>>(h, a2s, a2d, as_, ad_, N);
    agg_kernel<<<N, 128, 0, stream>>>(h, offs, esrc, as_, ad_, b2v, xbuf, N);

    // ---- MLP head ----
    gemm_mfma<true><<<ggrid, 256, 0, stream>>>(xbuf, WmtH, WmtL, bm1, h, N, Hh, Hh);
    final_kernel<<<nb4, 256, 0, stream>>>(h, Wm2, bm2, out, N, Aout);

    // ---- silent guard ----
    guard_kernel<<<1, 64, 0, stream>>>(out);
}

// Round 10
// 302.660 us; speedup vs baseline: 1.9547x; 1.0266x over previous
//
#include <hip/hip_runtime.h>
#include <hip/hip_bf16.h>
#include <math.h>
#include <stdio.h>

typedef __attribute__((ext_vector_type(8))) short short8;   // 8 bf16 (4 VGPRs)
typedef __attribute__((ext_vector_type(4))) float f32x4;
typedef __attribute__((ext_vector_type(4))) unsigned short us4;
typedef unsigned short us_t;

__device__ __forceinline__ float us2f(unsigned short u) {
    return __uint_as_float(((unsigned)u) << 16);
}
__device__ __forceinline__ unsigned short f2us_rtn(float f) {
    return (unsigned short)__bfloat16_as_ushort(__float2bfloat16(f));  // RTN
}

// W [K][N] fp32 -> Wt hi/lo bf16 planes, n-major [N][K]; 3 matrices fused
__global__ void prep3_wT(const float* __restrict__ Wa, const float* __restrict__ Wb,
                         const float* __restrict__ Wc,
                         unsigned short* __restrict__ HiA, unsigned short* __restrict__ LoA,
                         unsigned short* __restrict__ HiB, unsigned short* __restrict__ LoB,
                         unsigned short* __restrict__ HiC, unsigned short* __restrict__ LoC,
                         int K, int Nn) {
    const int tot = K * Nn;
    int idx = blockIdx.x * blockDim.x + threadIdx.x;
    if (idx >= 3 * tot) return;
    const float* W;
    unsigned short *Hi, *Lo;
    if (idx < tot) { W = Wa; Hi = HiA; Lo = LoA; }
    else if (idx < 2 * tot) { W = Wb; Hi = HiB; Lo = LoB; idx -= tot; }
    else { W = Wc; Hi = HiC; Lo = LoC; idx -= 2 * tot; }
    const int n = idx / K, k = idx - n * K;
    const float f = W[(size_t)k * Nn + n];
    const unsigned u = __float_as_uint(f);
    Hi[idx] = (unsigned short)(u >> 16);
    const float hf = __uint_as_float(u & 0xffff0000u);
    Lo[idx] = (unsigned short)(__float_as_uint(f - hf) >> 16);
}

// obs fp32 -> bf16 (RTN), vectorized
__global__ void prep_obs(const float* __restrict__ X, unsigned short* __restrict__ Xb, int tot8) {
    const int i = blockIdx.x * blockDim.x + threadIdx.x;
    if (i >= tot8) return;
    const float4 a = *(const float4*)(X + (size_t)i * 8);
    const float4 b = *(const float4*)(X + (size_t)i * 8 + 4);
    short8 o;
    const float f[8] = {a.x, a.y, a.z, a.w, b.x, b.y, b.z, b.w};
#pragma unroll
    for (int e = 0; e < 8; e++) o[e] = (short)f2us_rtn(f[e]);
    *(short8*)(Xb + (size_t)i * 8) = o;
}

// ---------------- MFMA GEMM: C = A(bf16) * B (+bias, relu), bf16 out ---------
// 64x128 tile/block, BK=64, 256 thr (4 waves 2x2). bf16x2: A bf16, B hi+lo.
#define LP 72
template <bool BIASRELU>
__global__ __launch_bounds__(256) void gemm_mfma(const unsigned short* __restrict__ A,
                                                 const unsigned short* __restrict__ BtHi,
                                                 const unsigned short* __restrict__ BtLo,
                                                 const float* __restrict__ bias,
                                                 unsigned short* __restrict__ C,
                                                 int M, int Nn, int K) {
    __shared__ unsigned short sA[64 * LP];
    __shared__ unsigned short sBh[128 * LP];
    __shared__ unsigned short sBl[128 * LP];
    const int tid = threadIdx.x;
    const int wave = tid >> 6, lane = tid & 63;
    const int m16 = lane & 15, quad = lane >> 4;
    const int row0 = blockIdx.x * 64, col0 = blockIdx.y * 128;
    const int wr = (wave >> 1) * 32, wc = (wave & 1) * 64;
    // A staging: row = tid>>2 (64), k-chunk = (tid&3)*8, two loads 32 us apart
    const int ar = tid >> 2, akc = (tid & 3) * 8;
    // B staging: kc = (tid&7)*8, colbase = tid>>3 (32 cols per pass)
    const int bkc = (tid & 7) * 8, bcb = tid >> 3;

    f32x4 acc[2][4] = {};
    for (int k0 = 0; k0 < K; k0 += 64) {
        // ---- stage A (copy bf16) ----
        {
            const int gr = (row0 + ar) < M ? (row0 + ar) : (M - 1);
            const unsigned short* Ap = A + (size_t)gr * K + k0 + akc;
            *(short8*)&sA[ar * LP + akc]      = *(const short8*)Ap;
            *(short8*)&sA[ar * LP + akc + 32] = *(const short8*)(Ap + 32);
        }
        // ---- stage B (hi+lo planes, lane-contiguous) ----
#pragma unroll
        for (int q = 0; q < 8; q++) {
            const int pl = q >> 2;
            const int colq = bcb + 32 * (q & 3);
            const unsigned short* Bp = (pl ? BtLo : BtHi) + (size_t)(col0 + colq) * K + k0 + bkc;
            unsigned short* sB = pl ? sBl : sBh;
            *(short8*)&sB[colq * LP + bkc] = *(const short8*)Bp;
        }
        __syncthreads();
        // ---- MFMA ----
#pragma unroll
        for (int ks = 0; ks < 2; ks++) {
            short8 ah[2];
#pragma unroll
            for (int mi = 0; mi < 2; mi++)
                ah[mi] = *(const short8*)&sA[(wr + mi * 16 + m16) * LP + ks * 32 + quad * 8];
#pragma unroll
            for (int ni = 0; ni < 4; ni++) {
                const int nb = (wc + ni * 16 + m16) * LP + ks * 32 + quad * 8;
                const short8 bh = *(const short8*)&sBh[nb];
                const short8 bl = *(const short8*)&sBl[nb];
#pragma unroll
                for (int mi = 0; mi < 2; mi++) {
                    acc[mi][ni] = __builtin_amdgcn_mfma_f32_16x16x32_bf16(ah[mi], bh, acc[mi][ni], 0, 0, 0);
                    acc[mi][ni] = __builtin_amdgcn_mfma_f32_16x16x32_bf16(ah[mi], bl, acc[mi][ni], 0, 0, 0);
                }
            }
        }
        __syncthreads();
    }
    // epilogue: C/D layout col=lane&15, row=quad*4+r [m89-verified]
#pragma unroll
    for (int mi = 0; mi < 2; mi++) {
        const int orow_base = row0 + wr + mi * 16 + quad * 4;
#pragma unroll
        for (int ni = 0; ni < 4; ni++) {
            const int ocol = col0 + wc + ni * 16 + m16;
#pragma unroll
            for (int r = 0; r < 4; r++) {
                const int orow = orow_base + r;
                if (orow < M) {
                    float v = acc[mi][ni][r];
                    if (BIASRELU) { v += bias[ocol]; v = fmaxf(v, 0.f); }
                    C[(size_t)orow * Nn + ocol] = f2us_rtn(v);
                }
            }
        }
    }
}
#undef LP

// ---------------- per-node attention dots (bf16 h) ---------------------------
__global__ __launch_bounds__(256) void dots_kernel(const unsigned short* __restrict__ hb,
                                                   const float* __restrict__ asrc,
                                                   const float* __restrict__ adst,
                                                   float* __restrict__ as_,
                                                   float* __restrict__ ad_, int N) {
    const int wave = threadIdx.x >> 6, lane = threadIdx.x & 63;
    const int n = blockIdx.x * 4 + wave;
    if (n >= N) return;
    const int f = lane * 4;
    const us4 v = *(const us4*)(hb + (size_t)n * 256 + f);
    float s1 = 0.f, s2 = 0.f;
#pragma unroll
    for (int e = 0; e < 4; e++) {
        const float x = us2f(v[e]);
        s1 = fmaf(x, asrc[f + e], s1);
        s2 = fmaf(x, adst[f + e], s2);
    }
#pragma unroll
    for (int off = 32; off; off >>= 1) {
        s1 += __shfl_down(s1, off);
        s2 += __shfl_down(s2, off);
    }
    if (lane == 0) { as_[n] = s1; ad_[n] = s2; }
}

// ---------------- CSR build ----------------
__global__ void init_deg(int* __restrict__ deg, int N) {
    const int i = blockIdx.x * blockDim.x + threadIdx.x;
    if (i < N) deg[i] = 0;
}

__global__ void count_kernel(const int* __restrict__ dstA, int* __restrict__ deg, int E, int Etot) {
    const int e = blockIdx.x * blockDim.x + threadIdx.x;
    if (e >= Etot) return;
    const int d = (e < E) ? dstA[e] : (e - E);
    atomicAdd(&deg[d], 1);
}

__global__ __launch_bounds__(1024) void scan_kernel(const int* __restrict__ deg,
                                                    int* __restrict__ offs,
                                                    int* __restrict__ cursor, int N) {
    __shared__ int sums[1024];
    const int t = threadIdx.x;
    const int chunk = (N + 1023) / 1024;
    const int start = t * chunk;
    int s = 0;
    for (int i = 0; i < chunk; i++) {
        const int p = start + i;
        if (p < N) s += deg[p];
    }
    sums[t] = s;
    __syncthreads();
    for (int off = 1; off < 1024; off <<= 1) {
        const int add = (t >= off) ? sums[t - off] : 0;
        __syncthreads();
        sums[t] += add;
        __syncthreads();
    }
    int run = (t > 0) ? sums[t - 1] : 0;
    for (int i = 0; i < chunk; i++) {
        const int p = start + i;
        if (p < N) { offs[p] = run; cursor[p] = run; run += deg[p]; }
    }
    if (t == 0) offs[N] = sums[1023];
}

__global__ void scatter_kernel(const int* __restrict__ srcA, const int* __restrict__ dstA,
                               int* __restrict__ cursor, int* __restrict__ esrc, int E, int Etot) {
    const int e = blockIdx.x * blockDim.x + threadIdx.x;
    if (e >= Etot) return;
    int s, d;
    if (e < E) { s = srcA[e]; d = dstA[e]; } else { s = d = e - E; }
    const int slot = atomicAdd(&cursor[d], 1);
    esrc[slot] = s;
}

// ---- fused softmax+aggregation over bf16 h: 128 thr/node, bf16 out ----------
__global__ __launch_bounds__(128) void agg_kernel(const unsigned short* __restrict__ hb,
                                                  const int* __restrict__ offs,
                                                  const int* __restrict__ esrc,
                                                  const float* __restrict__ as_,
                                                  const float* __restrict__ ad_,
                                                  const float* __restrict__ bias,
                                                  unsigned short* __restrict__ xout, int N) {
    const int n = blockIdx.x;
    const int f0 = threadIdx.x * 2;
    const int b = offs[n], e2 = offs[n + 1];
    const float adn = ad_[n];
    float ax = 0.f, ay = 0.f, wsum = 0.f;
    int j = b;
    for (; j + 8 <= e2; j += 8) {
        int s[8];
#pragma unroll
        for (int u = 0; u < 8; u++) s[u] = esrc[j + u];
        unsigned pv[8];
#pragma unroll
        for (int u = 0; u < 8; u++) pv[u] = *(const unsigned*)(hb + (size_t)s[u] * 256 + f0);
        float w[8];
#pragma unroll
        for (int u = 0; u < 8; u++) {
            float v = as_[s[u]] + adn;
            v = v > 0.f ? v : 0.2f * v;
            w[u] = __expf(v);
        }
#pragma unroll
        for (int u = 0; u < 8; u++) {
            ax = fmaf(w[u], us2f((unsigned short)(pv[u] & 0xffffu)), ax);
            ay = fmaf(w[u], us2f((unsigned short)(pv[u] >> 16)), ay);
            wsum += w[u];
        }
    }
    for (; j < e2; j++) {
        const int s = esrc[j];
        float v = as_[s] + adn;
        v = v > 0.f ? v : 0.2f * v;
        const float w = __expf(v);
        const unsigned pv = *(const unsigned*)(hb + (size_t)s * 256 + f0);
        ax = fmaf(w, us2f((unsigned short)(pv & 0xffffu)), ax);
        ay = fmaf(w, us2f((unsigned short)(pv >> 16)), ay);
        wsum += w;
    }
    const float inv = 1.0f / (wsum + 1e-16f);
    float rx = ax * inv + bias[f0];
    float ry = ay * inv + bias[f0 + 1];
    rx = rx > 0.f ? rx : 0.f;
    ry = ry > 0.f ? ry : 0.f;
    const unsigned pack = (unsigned)f2us_rtn(rx) | ((unsigned)f2us_rtn(ry) << 16);
    *(unsigned*)(xout + (size_t)n * 256 + f0) = pack;
}

// ---------------- final head: tanh(x @ Wm2 + bm2), bf16 x, fp32 out ----------
__global__ __launch_bounds__(256) void final_kernel(const unsigned short* __restrict__ xb,
                                                    const float* __restrict__ W,
                                                    const float* __restrict__ bias,
                                                    float* __restrict__ out, int N, int A) {
    const int wave = threadIdx.x >> 6, lane = threadIdx.x & 63;
    const int n = blockIdx.x * 4 + wave;
    if (n >= N) return;
    const int k0 = lane * 4;
    const us4 v = *(const us4*)(xb + (size_t)n * 256 + k0);
    float p[8] = {};
#pragma unroll
    for (int e = 0; e < 4; e++) {
        const float xv = us2f(v[e]);
#pragma unroll
        for (int a = 0; a < 8; a++) p[a] = fmaf(xv, W[(k0 + e) * A + a], p[a]);
    }
#pragma unroll
    for (int off = 32; off; off >>= 1)
#pragma unroll
        for (int a = 0; a < 8; a++) p[a] += __shfl_down(p[a], off);
    if (lane == 0) {
        for (int a = 0; a < A; a++) out[(size_t)n * A + a] = tanhf(p[a] + bias[a]);
    }
}

// ---------------- silent guard ----------------------------------------------
__global__ void guard_kernel(const float* __restrict__ out) {
    if (threadIdx.x != 0 || blockIdx.x != 0) return;
    const float o0 = out[0];
    if (fabsf(o0) > 0.f && o0 == o0) return;
    printf("GUARD o0=%e o1=%e\n", (double)o0, (double)out[1]);
}

extern "C" void kernel_launch(void* const* d_in, const int* in_sizes, int n_in,
                              void* d_out, int out_size, void* d_ws, size_t ws_size,
                              hipStream_t stream) {
    const float* obs = (const float*)d_in[0];
    const int* eidx  = (const int*)d_in[1];
    const float* W1  = (const float*)d_in[2];
    const float* a1s = (const float*)d_in[3];
    const float* a1d = (const float*)d_in[4];
    const float* b1  = (const float*)d_in[5];
    const float* W2  = (const float*)d_in[6];
    const float* a2s = (const float*)d_in[7];
    const float* a2d = (const float*)d_in[8];
    const float* b2v = (const float*)d_in[9];
    const float* Wm1 = (const float*)d_in[10];
    const float* bm1 = (const float*)d_in[11];
    const float* Wm2 = (const float*)d_in[12];
    const float* bm2 = (const float*)d_in[13];
    float* out = (float*)d_out;

    const int Hh = in_sizes[3];            // 256
    const int Dd = in_sizes[2] / Hh;       // 256
    const int N  = in_sizes[0] / Dd;       // 20000
    const int E  = in_sizes[1] / 2;        // 320000
    const int Etot = E + N;                // 340000 (with self-loops)
    const int Aout = in_sizes[12] / Hh;    // 8

    const int* srcA = eidx;
    const int* dstA = eidx + E;

    size_t off = 0;
    char* ws = (char*)d_ws;
    auto alloc = [&](size_t bytes) -> char* {
        char* p = ws + off;
        off = (off + bytes + 15) & ~(size_t)15;
        return p;
    };
    unsigned short* obs_b = (unsigned short*)alloc((size_t)N * Dd * 2);
    unsigned short* h     = (unsigned short*)alloc((size_t)N * Hh * 2);
    unsigned short* xb    = (unsigned short*)alloc((size_t)N * Hh * 2);
    float* as_   = (float*)alloc((size_t)N * 4);
    float* ad_   = (float*)alloc((size_t)N * 4);
    int* deg     = (int*)alloc((size_t)N * 4);
    int* offs    = (int*)alloc((size_t)(N + 1) * 4);
    int* cursor  = (int*)alloc((size_t)N * 4);
    int* esrc    = (int*)alloc((size_t)Etot * 4);
    const size_t wsz = (size_t)Dd * Hh;    // 65536
    unsigned short* W1tH = (unsigned short*)alloc(wsz * 2);
    unsigned short* W1tL = (unsigned short*)alloc(wsz * 2);
    unsigned short* W2tH = (unsigned short*)alloc(wsz * 2);
    unsigned short* W2tL = (unsigned short*)alloc(wsz * 2);
    unsigned short* WmtH = (unsigned short*)alloc(wsz * 2);
    unsigned short* WmtL = (unsigned short*)alloc(wsz * 2);

    const int eb = 256;
    const int eg = (Etot + eb - 1) / eb;
    const int ng = (N + 255) / 256;
    const dim3 ggrid((N + 63) / 64, Hh / 128);   // 313 x 2
    const int nb4 = (N + 3) / 4;

    // ---- weight + obs prep ----
    const int p3 = (3 * (int)wsz + 255) / 256;
    prep3_wT<<<p3, 256, 0, stream>>>(W1, W2, Wm1, W1tH, W1tL, W2tH, W2tL, WmtH, WmtL, Dd, Hh);
    const int tot8 = (N * Dd) / 8;
    prep_obs<<<(tot8 + 255) / 256, 256, 0, stream>>>(obs, obs_b, tot8);

    // ---- CSR build (topology shared by both GAT layers) ----
    init_deg<<<ng, 256, 0, stream>>>(deg, N);
    count_kernel<<<eg, eb, 0, stream>>>(dstA, deg, E, Etot);
    scan_kernel<<<1, 1024, 0, stream>>>(deg, offs, cursor, N);
    scatter_kernel<<<eg, eb, 0, stream>>>(srcA, dstA, cursor, esrc, E, Etot);

    // ---- GAT layer 1 ----
    gemm_mfma<false><<<ggrid, 256, 0, stream>>>(obs_b, W1tH, W1tL, nullptr, h, N, Hh, Dd);
    dots_kernel<<<nb4, 256, 0, stream>>>(h, a1s, a1d, as_, ad_, N);
    agg_kernel<<<N, 128, 0, stream>>>(h, offs, esrc, as_, ad_, b1, xb, N);

    // ---- GAT layer 2 ----
    gemm_mfma<false><<<ggrid, 256, 0, stream>>>(xb, W2tH, W2tL, nullptr, h, N, Hh, Hh);
    dots_kernel<<<nb4, 256, 0, stream>>>(h, a2s, a2d, as_, ad_, N);
    agg_kernel<<<N, 128, 0, stream>>>(h, offs, esrc, as_, ad_, b2v, xb, N);

    // ---- MLP head ----
    gemm_mfma<true><<<ggrid, 256, 0, stream>>>(xb, WmtH, WmtL, bm1, h, N, Hh, Hh);
    final_kernel<<<nb4, 256, 0, stream>>>(h, Wm2, bm2, out, N, Aout);

    // ---- silent guard ----
    guard_kernel<<<1, 64, 0, stream>>>(out);
}

// Round 11
// 284.623 us; speedup vs baseline: 2.0786x; 1.0634x over previous
//
#include <hip/hip_runtime.h>
#include <hip/hip_bf16.h>
#include <math.h>
#include <stdio.h>

typedef __attribute__((ext_vector_type(8))) short short8;   // 8 bf16 (4 VGPRs)
typedef __attribute__((ext_vector_type(4))) float f32x4;
typedef __attribute__((ext_vector_type(4))) unsigned short us4;

__device__ __forceinline__ float us2f(unsigned short u) {
    return __uint_as_float(((unsigned)u) << 16);
}
__device__ __forceinline__ unsigned short f2us_rtn(float f) {
    return (unsigned short)__bfloat16_as_ushort(__float2bfloat16(f));  // RTN
}

// ---- mega-prep: W^T hi/lo planes x3, obs->bf16, zero-init (deg, as/ad x4) ---
__global__ void prep_all(const float* __restrict__ Wa, const float* __restrict__ Wb,
                         const float* __restrict__ Wc,
                         unsigned short* __restrict__ HiA, unsigned short* __restrict__ LoA,
                         unsigned short* __restrict__ HiB, unsigned short* __restrict__ LoB,
                         unsigned short* __restrict__ HiC, unsigned short* __restrict__ LoC,
                         const float* __restrict__ X, unsigned short* __restrict__ Xb,
                         float* __restrict__ as1, float* __restrict__ ad1,
                         float* __restrict__ as2, float* __restrict__ ad2,
                         int* __restrict__ deg,
                         int K, int Nn, int N, int tot8) {
    const int tot = K * Nn;
    int idx = blockIdx.x * blockDim.x + threadIdx.x;
    if (idx < 3 * tot) {
        const float* W;
        unsigned short *Hi, *Lo;
        if (idx < tot) { W = Wa; Hi = HiA; Lo = LoA; }
        else if (idx < 2 * tot) { W = Wb; Hi = HiB; Lo = LoB; idx -= tot; }
        else { W = Wc; Hi = HiC; Lo = LoC; idx -= 2 * tot; }
        const int n = idx / K, k = idx - n * K;
        const float f = W[(size_t)k * Nn + n];
        const unsigned u = __float_as_uint(f);
        Hi[idx] = (unsigned short)(u >> 16);
        const float hf = __uint_as_float(u & 0xffff0000u);
        Lo[idx] = (unsigned short)(__float_as_uint(f - hf) >> 16);
        return;
    }
    idx -= 3 * tot;
    if (idx < 5 * N) {   // zero-init block
        if (idx < N) as1[idx] = 0.f;
        else if (idx < 2 * N) ad1[idx - N] = 0.f;
        else if (idx < 3 * N) as2[idx - 2 * N] = 0.f;
        else if (idx < 4 * N) ad2[idx - 3 * N] = 0.f;
        else deg[idx - 4 * N] = 0;
        return;
    }
    idx -= 5 * N;
    if (idx < tot8) {    // obs -> bf16
        const float4 a = *(const float4*)(X + (size_t)idx * 8);
        const float4 b = *(const float4*)(X + (size_t)idx * 8 + 4);
        short8 o;
        const float f[8] = {a.x, a.y, a.z, a.w, b.x, b.y, b.z, b.w};
#pragma unroll
        for (int e = 0; e < 8; e++) o[e] = (short)f2us_rtn(f[e]);
        *(short8*)(Xb + (size_t)idx * 8) = o;
    }
}

// ---------------- MFMA GEMM + optional fused dots ----------------------------
// 64x128 tile/block, BK=64, 256 thr (4 waves 2x2). A bf16, B bf16 (hi plane).
// DOTS: epilogue reduces v·a_src / v·a_dst over cols, atomicAdd per row.
#define LP 72
template <bool BIASRELU, bool DOTS>
__global__ __launch_bounds__(256) void gemm_mfma(const unsigned short* __restrict__ A,
                                                 const unsigned short* __restrict__ Bt,
                                                 const float* __restrict__ bias,
                                                 const float* __restrict__ avs,
                                                 const float* __restrict__ avd,
                                                 float* __restrict__ as_,
                                                 float* __restrict__ ad_,
                                                 unsigned short* __restrict__ C,
                                                 int M, int Nn, int K) {
    __shared__ unsigned short sA[64 * LP];
    __shared__ unsigned short sB[128 * LP];
    const int tid = threadIdx.x;
    const int wave = tid >> 6, lane = tid & 63;
    const int m16 = lane & 15, quad = lane >> 4;
    const int row0 = blockIdx.x * 64, col0 = blockIdx.y * 128;
    const int wr = (wave >> 1) * 32, wc = (wave & 1) * 64;
    const int ar = tid >> 2, akc = (tid & 3) * 8;
    const int bkc = (tid & 7) * 8, bcb = tid >> 3;

    f32x4 acc[2][4] = {};
    for (int k0 = 0; k0 < K; k0 += 64) {
        {
            const int gr = (row0 + ar) < M ? (row0 + ar) : (M - 1);
            const unsigned short* Ap = A + (size_t)gr * K + k0 + akc;
            *(short8*)&sA[ar * LP + akc]      = *(const short8*)Ap;
            *(short8*)&sA[ar * LP + akc + 32] = *(const short8*)(Ap + 32);
        }
#pragma unroll
        for (int q = 0; q < 4; q++) {
            const int colq = bcb + 32 * q;
            *(short8*)&sB[colq * LP + bkc] =
                *(const short8*)(Bt + (size_t)(col0 + colq) * K + k0 + bkc);
        }
        __syncthreads();
#pragma unroll
        for (int ks = 0; ks < 2; ks++) {
            short8 ah[2];
#pragma unroll
            for (int mi = 0; mi < 2; mi++)
                ah[mi] = *(const short8*)&sA[(wr + mi * 16 + m16) * LP + ks * 32 + quad * 8];
#pragma unroll
            for (int ni = 0; ni < 4; ni++) {
                const short8 bv = *(const short8*)&sB[(wc + ni * 16 + m16) * LP + ks * 32 + quad * 8];
#pragma unroll
                for (int mi = 0; mi < 2; mi++)
                    acc[mi][ni] = __builtin_amdgcn_mfma_f32_16x16x32_bf16(ah[mi], bv, acc[mi][ni], 0, 0, 0);
            }
        }
        __syncthreads();
    }
    // epilogue: C/D layout col=lane&15, row=quad*4+r [m89-verified]
    float ps[2][4] = {}, pd[2][4] = {};
#pragma unroll
    for (int mi = 0; mi < 2; mi++) {
        const int orow_base = row0 + wr + mi * 16 + quad * 4;
#pragma unroll
        for (int ni = 0; ni < 4; ni++) {
            const int ocol = col0 + wc + ni * 16 + m16;
            float asv = 0.f, adv = 0.f;
            if (DOTS) { asv = avs[ocol]; adv = avd[ocol]; }
#pragma unroll
            for (int r = 0; r < 4; r++) {
                const int orow = orow_base + r;
                if (orow < M) {
                    float v = acc[mi][ni][r];
                    if (BIASRELU) { v += bias[ocol]; v = fmaxf(v, 0.f); }
                    C[(size_t)orow * Nn + ocol] = f2us_rtn(v);
                    if (DOTS) { ps[mi][r] = fmaf(v, asv, ps[mi][r]); pd[mi][r] = fmaf(v, adv, pd[mi][r]); }
                }
            }
        }
    }
    if (DOTS) {
#pragma unroll
        for (int mi = 0; mi < 2; mi++)
#pragma unroll
            for (int r = 0; r < 4; r++) {
#pragma unroll
                for (int off = 1; off < 16; off <<= 1) {
                    ps[mi][r] += __shfl_xor(ps[mi][r], off);
                    pd[mi][r] += __shfl_xor(pd[mi][r], off);
                }
            }
        if (m16 == 0) {
#pragma unroll
            for (int mi = 0; mi < 2; mi++) {
                const int orow_base = row0 + wr + mi * 16 + quad * 4;
#pragma unroll
                for (int r = 0; r < 4; r++) {
                    const int orow = orow_base + r;
                    if (orow < M) {
                        atomicAdd(&as_[orow], ps[mi][r]);
                        atomicAdd(&ad_[orow], pd[mi][r]);
                    }
                }
            }
        }
    }
}
#undef LP

// ---------------- CSR build ----------------
__global__ void count_kernel(const int* __restrict__ dstA, int* __restrict__ deg, int E, int Etot) {
    const int e = blockIdx.x * blockDim.x + threadIdx.x;
    if (e >= Etot) return;
    const int d = (e < E) ? dstA[e] : (e - E);
    atomicAdd(&deg[d], 1);
}

__global__ __launch_bounds__(1024) void scan_kernel(const int* __restrict__ deg,
                                                    int* __restrict__ offs,
                                                    int* __restrict__ cursor, int N) {
    __shared__ int sums[1024];
    const int t = threadIdx.x;
    const int chunk = (N + 1023) / 1024;
    const int start = t * chunk;
    int s = 0;
    for (int i = 0; i < chunk; i++) {
        const int p = start + i;
        if (p < N) s += deg[p];
    }
    sums[t] = s;
    __syncthreads();
    for (int off = 1; off < 1024; off <<= 1) {
        const int add = (t >= off) ? sums[t - off] : 0;
        __syncthreads();
        sums[t] += add;
        __syncthreads();
    }
    int run = (t > 0) ? sums[t - 1] : 0;
    for (int i = 0; i < chunk; i++) {
        const int p = start + i;
        if (p < N) { offs[p] = run; cursor[p] = run; run += deg[p]; }
    }
    if (t == 0) offs[N] = sums[1023];
}

__global__ void scatter_kernel(const int* __restrict__ srcA, const int* __restrict__ dstA,
                               int* __restrict__ cursor, int* __restrict__ esrc, int E, int Etot) {
    const int e = blockIdx.x * blockDim.x + threadIdx.x;
    if (e >= Etot) return;
    int s, d;
    if (e < E) { s = srcA[e]; d = dstA[e]; } else { s = d = e - E; }
    const int slot = atomicAdd(&cursor[d], 1);
    esrc[slot] = s;
}

// ---- fused softmax+aggregation over bf16 h: 128 thr/node, bf16 out ----------
__global__ __launch_bounds__(128) void agg_kernel(const unsigned short* __restrict__ hb,
                                                  const int* __restrict__ offs,
                                                  const int* __restrict__ esrc,
                                                  const float* __restrict__ as_,
                                                  const float* __restrict__ ad_,
                                                  const float* __restrict__ bias,
                                                  unsigned short* __restrict__ xout, int N) {
    const int n = blockIdx.x;
    const int f0 = threadIdx.x * 2;
    const int b = offs[n], e2 = offs[n + 1];
    const float adn = ad_[n];
    float ax = 0.f, ay = 0.f, wsum = 0.f;
    int j = b;
    for (; j + 8 <= e2; j += 8) {
        int s[8];
#pragma unroll
        for (int u = 0; u < 8; u++) s[u] = esrc[j + u];
        unsigned pv[8];
#pragma unroll
        for (int u = 0; u < 8; u++) pv[u] = *(const unsigned*)(hb + (size_t)s[u] * 256 + f0);
        float w[8];
#pragma unroll
        for (int u = 0; u < 8; u++) {
            float v = as_[s[u]] + adn;
            v = v > 0.f ? v : 0.2f * v;
            w[u] = __expf(v);
        }
#pragma unroll
        for (int u = 0; u < 8; u++) {
            ax = fmaf(w[u], us2f((unsigned short)(pv[u] & 0xffffu)), ax);
            ay = fmaf(w[u], us2f((unsigned short)(pv[u] >> 16)), ay);
            wsum += w[u];
        }
    }
    for (; j < e2; j++) {
        const int s = esrc[j];
        float v = as_[s] + adn;
        v = v > 0.f ? v : 0.2f * v;
        const float w = __expf(v);
        const unsigned pv = *(const unsigned*)(hb + (size_t)s * 256 + f0);
        ax = fmaf(w, us2f((unsigned short)(pv & 0xffffu)), ax);
        ay = fmaf(w, us2f((unsigned short)(pv >> 16)), ay);
        wsum += w;
    }
    const float inv = 1.0f / (wsum + 1e-16f);
    float rx = ax * inv + bias[f0];
    float ry = ay * inv + bias[f0 + 1];
    rx = rx > 0.f ? rx : 0.f;
    ry = ry > 0.f ? ry : 0.f;
    const unsigned pack = (unsigned)f2us_rtn(rx) | ((unsigned)f2us_rtn(ry) << 16);
    *(unsigned*)(xout + (size_t)n * 256 + f0) = pack;
}

// ---------------- final head: tanh(x @ Wm2 + bm2), bf16 x, fp32 out ----------
__global__ __launch_bounds__(256) void final_kernel(const unsigned short* __restrict__ xb,
                                                    const float* __restrict__ W,
                                                    const float* __restrict__ bias,
                                                    float* __restrict__ out, int N, int A) {
    const int wave = threadIdx.x >> 6, lane = threadIdx.x & 63;
    const int n = blockIdx.x * 4 + wave;
    if (n >= N) return;
    const int k0 = lane * 4;
    const us4 v = *(const us4*)(xb + (size_t)n * 256 + k0);
    float p[8] = {};
#pragma unroll
    for (int e = 0; e < 4; e++) {
        const float xv = us2f(v[e]);
#pragma unroll
        for (int a = 0; a < 8; a++) p[a] = fmaf(xv, W[(k0 + e) * A + a], p[a]);
    }
#pragma unroll
    for (int off = 32; off; off >>= 1)
#pragma unroll
        for (int a = 0; a < 8; a++) p[a] += __shfl_down(p[a], off);
    if (lane == 0) {
        for (int a = 0; a < A; a++) out[(size_t)n * A + a] = tanhf(p[a] + bias[a]);
    }
}

// ---------------- silent guard ----------------------------------------------
__global__ void guard_kernel(const float* __restrict__ out) {
    if (threadIdx.x != 0 || blockIdx.x != 0) return;
    const float o0 = out[0];
    if (fabsf(o0) > 0.f && o0 == o0) return;
    printf("GUARD o0=%e o1=%e\n", (double)o0, (double)out[1]);
}

extern "C" void kernel_launch(void* const* d_in, const int* in_sizes, int n_in,
                              void* d_out, int out_size, void* d_ws, size_t ws_size,
                              hipStream_t stream) {
    const float* obs = (const float*)d_in[0];
    const int* eidx  = (const int*)d_in[1];
    const float* W1  = (const float*)d_in[2];
    const float* a1s = (const float*)d_in[3];
    const float* a1d = (const float*)d_in[4];
    const float* b1  = (const float*)d_in[5];
    const float* W2  = (const float*)d_in[6];
    const float* a2s = (const float*)d_in[7];
    const float* a2d = (const float*)d_in[8];
    const float* b2v = (const float*)d_in[9];
    const float* Wm1 = (const float*)d_in[10];
    const float* bm1 = (const float*)d_in[11];
    const float* Wm2 = (const float*)d_in[12];
    const float* bm2 = (const float*)d_in[13];
    float* out = (float*)d_out;

    const int Hh = in_sizes[3];            // 256
    const int Dd = in_sizes[2] / Hh;       // 256
    const int N  = in_sizes[0] / Dd;       // 20000
    const int E  = in_sizes[1] / 2;        // 320000
    const int Etot = E + N;                // 340000 (with self-loops)
    const int Aout = in_sizes[12] / Hh;    // 8

    const int* srcA = eidx;
    const int* dstA = eidx + E;

    size_t off = 0;
    char* ws = (char*)d_ws;
    auto alloc = [&](size_t bytes) -> char* {
        char* p = ws + off;
        off = (off + bytes + 15) & ~(size_t)15;
        return p;
    };
    unsigned short* obs_b = (unsigned short*)alloc((size_t)N * Dd * 2);
    unsigned short* h     = (unsigned short*)alloc((size_t)N * Hh * 2);
    unsigned short* xb    = (unsigned short*)alloc((size_t)N * Hh * 2);
    float* as1   = (float*)alloc((size_t)N * 4);
    float* ad1   = (float*)alloc((size_t)N * 4);
    float* as2   = (float*)alloc((size_t)N * 4);
    float* ad2   = (float*)alloc((size_t)N * 4);
    int* deg     = (int*)alloc((size_t)N * 4);
    int* offs    = (int*)alloc((size_t)(N + 1) * 4);
    int* cursor  = (int*)alloc((size_t)N * 4);
    int* esrc    = (int*)alloc((size_t)Etot * 4);
    const size_t wsz = (size_t)Dd * Hh;    // 65536
    unsigned short* W1tH = (unsigned short*)alloc(wsz * 2);
    unsigned short* W1tL = (unsigned short*)alloc(wsz * 2);
    unsigned short* W2tH = (unsigned short*)alloc(wsz * 2);
    unsigned short* W2tL = (unsigned short*)alloc(wsz * 2);
    unsigned short* WmtH = (unsigned short*)alloc(wsz * 2);
    unsigned short* WmtL = (unsigned short*)alloc(wsz * 2);

    const int eb = 256;
    const int eg = (Etot + eb - 1) / eb;
    const dim3 ggrid((N + 63) / 64, Hh / 128);   // 313 x 2
    const int nb4 = (N + 3) / 4;

    // ---- mega prep: weights + obs cast + zero inits ----
    const int tot8 = (N * Dd) / 8;
    const int ptot = 3 * (int)wsz + 5 * N + tot8;
    prep_all<<<(ptot + 255) / 256, 256, 0, stream>>>(
        W1, W2, Wm1, W1tH, W1tL, W2tH, W2tL, WmtH, WmtL,
        obs, obs_b, as1, ad1, as2, ad2, deg, Dd, Hh, N, tot8);

    // ---- CSR build ----
    count_kernel<<<eg, eb, 0, stream>>>(dstA, deg, E, Etot);
    scan_kernel<<<1, 1024, 0, stream>>>(deg, offs, cursor, N);
    scatter_kernel<<<eg, eb, 0, stream>>>(srcA, dstA, cursor, esrc, E, Etot);

    // ---- GAT layer 1 (gemm + fused dots) ----
    gemm_mfma<false, true><<<ggrid, 256, 0, stream>>>(obs_b, W1tH, nullptr, a1s, a1d,
                                                      as1, ad1, h, N, Hh, Dd);
    agg_kernel<<<N, 128, 0, stream>>>(h, offs, esrc, as1, ad1, b1, xb, N);

    // ---- GAT layer 2 ----
    gemm_mfma<false, true><<<ggrid, 256, 0, stream>>>(xb, W2tH, nullptr, a2s, a2d,
                                                      as2, ad2, h, N, Hh, Hh);
    agg_kernel<<<N, 128, 0, stream>>>(h, offs, esrc, as2, ad2, b2v, xb, N);

    // ---- MLP head ----
    gemm_mfma<true, false><<<ggrid, 256, 0, stream>>>(xb, WmtH, bm1, nullptr, nullptr,
                                                      nullptr, nullptr, h, N, Hh, Hh);
    final_kernel<<<nb4, 256, 0, stream>>>(h, Wm2, bm2, out, N, Aout);

    // ---- silent guard ----
    guard_kernel<<<1, 64, 0, stream>>>(out);
}

// Round 12
// 265.961 us; speedup vs baseline: 2.2244x; 1.0702x over previous
//
#include <hip/hip_runtime.h>
#include <hip/hip_bf16.h>
#include <math.h>
#include <stdio.h>

typedef __attribute__((ext_vector_type(8))) short short8;   // 8 bf16 (4 VGPRs)
typedef __attribute__((ext_vector_type(4))) float f32x4;
typedef __attribute__((ext_vector_type(4))) unsigned short us4;

__device__ __forceinline__ float us2f(unsigned short u) {
    return __uint_as_float(((unsigned)u) << 16);
}
__device__ __forceinline__ unsigned short f2us_rtn(float f) {
    return (unsigned short)__bfloat16_as_ushort(__float2bfloat16(f));  // RTN
}

// ---- mega-prep: W^T bf16 x3, obs->bf16, zero-init (deg, as/ad x4) -----------
__global__ void prep_all(const float* __restrict__ Wa, const float* __restrict__ Wb,
                         const float* __restrict__ Wc,
                         unsigned short* __restrict__ TA, unsigned short* __restrict__ TB,
                         unsigned short* __restrict__ TC,
                         const float* __restrict__ X, unsigned short* __restrict__ Xb,
                         float* __restrict__ as1, float* __restrict__ ad1,
                         float* __restrict__ as2, float* __restrict__ ad2,
                         int* __restrict__ deg,
                         int K, int Nn, int N, int tot8) {
    const int tot = K * Nn;
    int idx = blockIdx.x * blockDim.x + threadIdx.x;
    if (idx < 3 * tot) {
        const float* W;
        unsigned short* T;
        if (idx < tot) { W = Wa; T = TA; }
        else if (idx < 2 * tot) { W = Wb; T = TB; idx -= tot; }
        else { W = Wc; T = TC; idx -= 2 * tot; }
        const int n = idx / K, k = idx - n * K;
        T[idx] = f2us_rtn(W[(size_t)k * Nn + n]);
        return;
    }
    idx -= 3 * tot;
    if (idx < 5 * N) {
        if (idx < N) as1[idx] = 0.f;
        else if (idx < 2 * N) ad1[idx - N] = 0.f;
        else if (idx < 3 * N) as2[idx - 2 * N] = 0.f;
        else if (idx < 4 * N) ad2[idx - 3 * N] = 0.f;
        else deg[idx - 4 * N] = 0;
        return;
    }
    idx -= 5 * N;
    if (idx < tot8) {
        const float4 a = *(const float4*)(X + (size_t)idx * 8);
        const float4 b = *(const float4*)(X + (size_t)idx * 8 + 4);
        short8 o;
        const float f[8] = {a.x, a.y, a.z, a.w, b.x, b.y, b.z, b.w};
#pragma unroll
        for (int e = 0; e < 8; e++) o[e] = (short)f2us_rtn(f[e]);
        *(short8*)(Xb + (size_t)idx * 8) = o;
    }
}

#define LP 72
// ---------------- MFMA GEMM + fused dots (GAT layers 1/2) --------------------
// 64x128 tile/block, BK=64, 256 thr (4 waves 2x2). A,B bf16, fp32 acc.
__global__ __launch_bounds__(256) void gemm_mfma(const unsigned short* __restrict__ A,
                                                 const unsigned short* __restrict__ Bt,
                                                 const float* __restrict__ avs,
                                                 const float* __restrict__ avd,
                                                 float* __restrict__ as_,
                                                 float* __restrict__ ad_,
                                                 unsigned short* __restrict__ C,
                                                 int M, int Nn, int K) {
    __shared__ unsigned short sA[64 * LP];
    __shared__ unsigned short sB[128 * LP];
    const int tid = threadIdx.x;
    const int wave = tid >> 6, lane = tid & 63;
    const int m16 = lane & 15, quad = lane >> 4;
    const int row0 = blockIdx.x * 64, col0 = blockIdx.y * 128;
    const int wr = (wave >> 1) * 32, wc = (wave & 1) * 64;
    const int ar = tid >> 2, akc = (tid & 3) * 8;
    const int bkc = (tid & 7) * 8, bcb = tid >> 3;

    f32x4 acc[2][4] = {};
    for (int k0 = 0; k0 < K; k0 += 64) {
        {
            const int gr = (row0 + ar) < M ? (row0 + ar) : (M - 1);
            const unsigned short* Ap = A + (size_t)gr * K + k0 + akc;
            *(short8*)&sA[ar * LP + akc]      = *(const short8*)Ap;
            *(short8*)&sA[ar * LP + akc + 32] = *(const short8*)(Ap + 32);
        }
#pragma unroll
        for (int q = 0; q < 4; q++) {
            const int colq = bcb + 32 * q;
            *(short8*)&sB[colq * LP + bkc] =
                *(const short8*)(Bt + (size_t)(col0 + colq) * K + k0 + bkc);
        }
        __syncthreads();
#pragma unroll
        for (int ks = 0; ks < 2; ks++) {
            short8 ah[2];
#pragma unroll
            for (int mi = 0; mi < 2; mi++)
                ah[mi] = *(const short8*)&sA[(wr + mi * 16 + m16) * LP + ks * 32 + quad * 8];
#pragma unroll
            for (int ni = 0; ni < 4; ni++) {
                const short8 bv = *(const short8*)&sB[(wc + ni * 16 + m16) * LP + ks * 32 + quad * 8];
#pragma unroll
                for (int mi = 0; mi < 2; mi++)
                    acc[mi][ni] = __builtin_amdgcn_mfma_f32_16x16x32_bf16(ah[mi], bv, acc[mi][ni], 0, 0, 0);
            }
        }
        __syncthreads();
    }
    // epilogue: C/D layout col=lane&15, row=quad*4+r [m89-verified]
    float ps[2][4] = {}, pd[2][4] = {};
#pragma unroll
    for (int mi = 0; mi < 2; mi++) {
        const int orow_base = row0 + wr + mi * 16 + quad * 4;
#pragma unroll
        for (int ni = 0; ni < 4; ni++) {
            const int ocol = col0 + wc + ni * 16 + m16;
            const float asv = avs[ocol], adv = avd[ocol];
#pragma unroll
            for (int r = 0; r < 4; r++) {
                const int orow = orow_base + r;
                if (orow < M) {
                    const float v = acc[mi][ni][r];
                    C[(size_t)orow * Nn + ocol] = f2us_rtn(v);
                    ps[mi][r] = fmaf(v, asv, ps[mi][r]);
                    pd[mi][r] = fmaf(v, adv, pd[mi][r]);
                }
            }
        }
    }
#pragma unroll
    for (int mi = 0; mi < 2; mi++)
#pragma unroll
        for (int r = 0; r < 4; r++)
#pragma unroll
            for (int off = 1; off < 16; off <<= 1) {
                ps[mi][r] += __shfl_xor(ps[mi][r], off);
                pd[mi][r] += __shfl_xor(pd[mi][r], off);
            }
    if (m16 == 0) {
#pragma unroll
        for (int mi = 0; mi < 2; mi++) {
            const int orow_base = row0 + wr + mi * 16 + quad * 4;
#pragma unroll
            for (int r = 0; r < 4; r++) {
                const int orow = orow_base + r;
                if (orow < M) {
                    atomicAdd(&as_[orow], ps[mi][r]);
                    atomicAdd(&ad_[orow], pd[mi][r]);
                }
            }
        }
    }
}

// ---------------- MLP gemm + fused head: out = tanh(relu(x@Wm1+bm1)@Wm2+bm2) -
// 64x256 tile/block (full width), BK=64, 4 waves (32r x 128c each).
__global__ __launch_bounds__(256) void gemm_head(const unsigned short* __restrict__ A,
                                                 const unsigned short* __restrict__ Bt,
                                                 const float* __restrict__ bias1,
                                                 const float* __restrict__ W2,
                                                 const float* __restrict__ bias2,
                                                 float* __restrict__ out,
                                                 int M, int K, int Aout) {
    __shared__ unsigned short sA[64 * LP];
    __shared__ unsigned short sB[256 * LP];
    __shared__ float pLDS[2][64][8];
    const int tid = threadIdx.x;
    const int wave = tid >> 6, lane = tid & 63;
    const int m16 = lane & 15, quad = lane >> 4;
    const int row0 = blockIdx.x * 64;
    const int wr = (wave >> 1) * 32, wc = (wave & 1) * 128;
    const int ar = tid >> 2, akc = (tid & 3) * 8;
    const int bkc = (tid & 7) * 8, bcb = tid >> 3;

    f32x4 acc[2][8] = {};
    for (int k0 = 0; k0 < K; k0 += 64) {
        {
            const int gr = (row0 + ar) < M ? (row0 + ar) : (M - 1);
            const unsigned short* Ap = A + (size_t)gr * K + k0 + akc;
            *(short8*)&sA[ar * LP + akc]      = *(const short8*)Ap;
            *(short8*)&sA[ar * LP + akc + 32] = *(const short8*)(Ap + 32);
        }
#pragma unroll
        for (int q = 0; q < 8; q++) {
            const int colq = bcb + 32 * q;
            *(short8*)&sB[colq * LP + bkc] =
                *(const short8*)(Bt + (size_t)colq * K + k0 + bkc);
        }
        __syncthreads();
#pragma unroll
        for (int ks = 0; ks < 2; ks++) {
            short8 ah[2];
#pragma unroll
            for (int mi = 0; mi < 2; mi++)
                ah[mi] = *(const short8*)&sA[(wr + mi * 16 + m16) * LP + ks * 32 + quad * 8];
#pragma unroll
            for (int ni = 0; ni < 8; ni++) {
                const short8 bv = *(const short8*)&sB[(wc + ni * 16 + m16) * LP + ks * 32 + quad * 8];
#pragma unroll
                for (int mi = 0; mi < 2; mi++)
                    acc[mi][ni] = __builtin_amdgcn_mfma_f32_16x16x32_bf16(ah[mi], bv, acc[mi][ni], 0, 0, 0);
            }
        }
        __syncthreads();
    }
    // head: p[mi][r][a] = sum_cols relu(acc + bm1) * W2[col][a]
    float p[2][4][8] = {};
#pragma unroll
    for (int ni = 0; ni < 8; ni++) {
        const int ocol = wc + ni * 16 + m16;
        const float b1v = bias1[ocol];
        float w2[8];
#pragma unroll
        for (int a = 0; a < 8; a++) w2[a] = W2[ocol * 8 + a];
#pragma unroll
        for (int mi = 0; mi < 2; mi++)
#pragma unroll
            for (int r = 0; r < 4; r++) {
                const float v = fmaxf(acc[mi][ni][r] + b1v, 0.f);
#pragma unroll
                for (int a = 0; a < 8; a++) p[mi][r][a] = fmaf(v, w2[a], p[mi][r][a]);
            }
    }
#pragma unroll
    for (int off = 1; off < 16; off <<= 1)
#pragma unroll
        for (int mi = 0; mi < 2; mi++)
#pragma unroll
            for (int r = 0; r < 4; r++)
#pragma unroll
                for (int a = 0; a < 8; a++) p[mi][r][a] += __shfl_xor(p[mi][r][a], off);
    if (m16 == 0) {
        const int half = wc >> 7;
#pragma unroll
        for (int mi = 0; mi < 2; mi++) {
            const int lrow = wr + mi * 16 + quad * 4;
#pragma unroll
            for (int r = 0; r < 4; r++)
#pragma unroll
                for (int a = 0; a < 8; a++) pLDS[half][lrow + r][a] = p[mi][r][a];
        }
    }
    __syncthreads();
#pragma unroll
    for (int u = 0; u < 2; u++) {
        const int idx = tid * 2 + u;
        const int lrow = idx >> 3, a = idx & 7;
        const int orow = row0 + lrow;
        if (orow < M && a < Aout)
            out[(size_t)orow * Aout + a] =
                tanhf(pLDS[0][lrow][a] + pLDS[1][lrow][a] + bias2[a]);
    }
}
#undef LP

// ---------------- CSR build ----------------
__global__ void count_kernel(const int* __restrict__ dstA, int* __restrict__ deg, int E, int Etot) {
    const int e = blockIdx.x * blockDim.x + threadIdx.x;
    if (e >= Etot) return;
    const int d = (e < E) ? dstA[e] : (e - E);
    atomicAdd(&deg[d], 1);
}

__global__ __launch_bounds__(1024) void scan_kernel(const int* __restrict__ deg,
                                                    int* __restrict__ offs,
                                                    int* __restrict__ cursor, int N) {
    __shared__ int sums[1024];
    const int t = threadIdx.x;
    const int chunk = (N + 1023) / 1024;
    const int start = t * chunk;
    int s = 0;
    for (int i = 0; i < chunk; i++) {
        const int p = start + i;
        if (p < N) s += deg[p];
    }
    sums[t] = s;
    __syncthreads();
    for (int off = 1; off < 1024; off <<= 1) {
        const int add = (t >= off) ? sums[t - off] : 0;
        __syncthreads();
        sums[t] += add;
        __syncthreads();
    }
    int run = (t > 0) ? sums[t - 1] : 0;
    for (int i = 0; i < chunk; i++) {
        const int p = start + i;
        if (p < N) { offs[p] = run; cursor[p] = run; run += deg[p]; }
    }
    if (t == 0) offs[N] = sums[1023];
}

__global__ void scatter_kernel(const int* __restrict__ srcA, const int* __restrict__ dstA,
                               int* __restrict__ cursor, int* __restrict__ esrc, int E, int Etot) {
    const int e = blockIdx.x * blockDim.x + threadIdx.x;
    if (e >= Etot) return;
    int s, d;
    if (e < E) { s = srcA[e]; d = dstA[e]; } else { s = d = e - E; }
    const int slot = atomicAdd(&cursor[d], 1);
    esrc[slot] = s;
}

// ---- fused softmax+aggregation: wave per node, 4 feats/lane, bf16 in/out ----
__global__ __launch_bounds__(256) void agg_kernel(const unsigned short* __restrict__ hb,
                                                  const int* __restrict__ offs,
                                                  const int* __restrict__ esrc,
                                                  const float* __restrict__ as_,
                                                  const float* __restrict__ ad_,
                                                  const float* __restrict__ bias,
                                                  unsigned short* __restrict__ xout, int N) {
    const int n = blockIdx.x * 4 + (threadIdx.x >> 6);
    if (n >= N) return;
    const int lane = threadIdx.x & 63;
    const int f0 = lane * 4;
    const int b = offs[n], e2 = offs[n + 1];
    const float adn = ad_[n];
    float a0 = 0.f, a1 = 0.f, a2 = 0.f, a3 = 0.f, wsum = 0.f;
    int j = b;
    for (; j + 8 <= e2; j += 8) {
        int s[8];
#pragma unroll
        for (int u = 0; u < 8; u++) s[u] = esrc[j + u];
        us4 pv[8];
#pragma unroll
        for (int u = 0; u < 8; u++) pv[u] = *(const us4*)(hb + (size_t)s[u] * 256 + f0);
        float w[8];
#pragma unroll
        for (int u = 0; u < 8; u++) {
            float v = as_[s[u]] + adn;
            v = v > 0.f ? v : 0.2f * v;
            w[u] = __expf(v);
        }
#pragma unroll
        for (int u = 0; u < 8; u++) {
            a0 = fmaf(w[u], us2f(pv[u][0]), a0);
            a1 = fmaf(w[u], us2f(pv[u][1]), a1);
            a2 = fmaf(w[u], us2f(pv[u][2]), a2);
            a3 = fmaf(w[u], us2f(pv[u][3]), a3);
            wsum += w[u];
        }
    }
    for (; j < e2; j++) {
        const int s = esrc[j];
        float v = as_[s] + adn;
        v = v > 0.f ? v : 0.2f * v;
        const float w = __expf(v);
        const us4 pv = *(const us4*)(hb + (size_t)s * 256 + f0);
        a0 = fmaf(w, us2f(pv[0]), a0);
        a1 = fmaf(w, us2f(pv[1]), a1);
        a2 = fmaf(w, us2f(pv[2]), a2);
        a3 = fmaf(w, us2f(pv[3]), a3);
        wsum += w;
    }
    const float inv = 1.0f / (wsum + 1e-16f);
    float r0 = fmaxf(a0 * inv + bias[f0], 0.f);
    float r1 = fmaxf(a1 * inv + bias[f0 + 1], 0.f);
    float r2 = fmaxf(a2 * inv + bias[f0 + 2], 0.f);
    float r3 = fmaxf(a3 * inv + bias[f0 + 3], 0.f);
    us4 o;
    o[0] = f2us_rtn(r0); o[1] = f2us_rtn(r1); o[2] = f2us_rtn(r2); o[3] = f2us_rtn(r3);
    *(us4*)(xout + (size_t)n * 256 + f0) = o;
}

extern "C" void kernel_launch(void* const* d_in, const int* in_sizes, int n_in,
                              void* d_out, int out_size, void* d_ws, size_t ws_size,
                              hipStream_t stream) {
    const float* obs = (const float*)d_in[0];
    const int* eidx  = (const int*)d_in[1];
    const float* W1  = (const float*)d_in[2];
    const float* a1s = (const float*)d_in[3];
    const float* a1d = (const float*)d_in[4];
    const float* b1  = (const float*)d_in[5];
    const float* W2  = (const float*)d_in[6];
    const float* a2s = (const float*)d_in[7];
    const float* a2d = (const float*)d_in[8];
    const float* b2v = (const float*)d_in[9];
    const float* Wm1 = (const float*)d_in[10];
    const float* bm1 = (const float*)d_in[11];
    const float* Wm2 = (const float*)d_in[12];
    const float* bm2 = (const float*)d_in[13];
    float* out = (float*)d_out;

    const int Hh = in_sizes[3];            // 256
    const int Dd = in_sizes[2] / Hh;       // 256
    const int N  = in_sizes[0] / Dd;       // 20000
    const int E  = in_sizes[1] / 2;        // 320000
    const int Etot = E + N;                // 340000 (with self-loops)
    const int Aout = in_sizes[12] / Hh;    // 8

    const int* srcA = eidx;
    const int* dstA = eidx + E;

    size_t off = 0;
    char* ws = (char*)d_ws;
    auto alloc = [&](size_t bytes) -> char* {
        char* p = ws + off;
        off = (off + bytes + 15) & ~(size_t)15;
        return p;
    };
    unsigned short* obs_b = (unsigned short*)alloc((size_t)N * Dd * 2);
    unsigned short* h     = (unsigned short*)alloc((size_t)N * Hh * 2);
    unsigned short* xb    = (unsigned short*)alloc((size_t)N * Hh * 2);
    float* as1   = (float*)alloc((size_t)N * 4);
    float* ad1   = (float*)alloc((size_t)N * 4);
    float* as2   = (float*)alloc((size_t)N * 4);
    float* ad2   = (float*)alloc((size_t)N * 4);
    int* deg     = (int*)alloc((size_t)N * 4);
    int* offs    = (int*)alloc((size_t)(N + 1) * 4);
    int* cursor  = (int*)alloc((size_t)N * 4);
    int* esrc    = (int*)alloc((size_t)Etot * 4);
    const size_t wsz = (size_t)Dd * Hh;    // 65536
    unsigned short* W1t = (unsigned short*)alloc(wsz * 2);
    unsigned short* W2t = (unsigned short*)alloc(wsz * 2);
    unsigned short* Wmt = (unsigned short*)alloc(wsz * 2);

    const int eb = 256;
    const int eg = (Etot + eb - 1) / eb;
    const dim3 ggrid((N + 63) / 64, Hh / 128);   // 313 x 2
    const int nrow = (N + 63) / 64;              // 313

    // ---- mega prep ----
    const int tot8 = (N * Dd) / 8;
    const int ptot = 3 * (int)wsz + 5 * N + tot8;
    prep_all<<<(ptot + 255) / 256, 256, 0, stream>>>(
        W1, W2, Wm1, W1t, W2t, Wmt, obs, obs_b, as1, ad1, as2, ad2, deg, Dd, Hh, N, tot8);

    // ---- CSR build ----
    count_kernel<<<eg, eb, 0, stream>>>(dstA, deg, E, Etot);
    scan_kernel<<<1, 1024, 0, stream>>>(deg, offs, cursor, N);
    scatter_kernel<<<eg, eb, 0, stream>>>(srcA, dstA, cursor, esrc, E, Etot);

    // ---- GAT layer 1 ----
    gemm_mfma<<<ggrid, 256, 0, stream>>>(obs_b, W1t, a1s, a1d, as1, ad1, h, N, Hh, Dd);
    agg_kernel<<<(N + 3) / 4, 256, 0, stream>>>(h, offs, esrc, as1, ad1, b1, xb, N);

    // ---- GAT layer 2 ----
    gemm_mfma<<<ggrid, 256, 0, stream>>>(xb, W2t, a2s, a2d, as2, ad2, h, N, Hh, Hh);
    agg_kernel<<<(N + 3) / 4, 256, 0, stream>>>(h, offs, esrc, as2, ad2, b2v, xb, N);

    // ---- MLP + head (fused) ----
    gemm_head<<<nrow, 256, 0, stream>>>(xb, Wmt, bm1, Wm2, bm2, out, N, Hh, Aout);
}